// Round 8
// baseline (568.058 us; speedup 1.0000x reference)
//
#include <hip/hip_runtime.h>
#include <math.h>

#define MCENT 16
#define KNN   64
#define NBINS 512
#define CAP   7936
#define FCAP  2048
#define FPSB  512
#define FPST  256
#define MLPT  1024

__device__ __forceinline__ float gelu_f(float x){
    return 0.5f * x * (1.0f + erff(x * 0.70710678118654752440f));
}

// ---------------- FPS step k: no device-side grid sync, 16 graph launches ----------------
// Step k: (a) reduce step k-1's block partials -> center k (redundantly per block;
// kernel boundary is the coherence point), (b) write cxy/outC[k] (block 0),
// (c) if k < MCENT-1: update min_d vs center k (2 pts/thread, float4), emit partial.
// k==0 additionally zero-inits ghist/cnt.
__global__ __launch_bounds__(FPST) void fps_step(
    const float* __restrict__ P, int N,
    float* __restrict__ min_d,                  // [N] in ws, persists across steps
    unsigned long long* __restrict__ partials,  // [MCENT][FPSB]
    int k,
    float* __restrict__ cxy,
    float* __restrict__ outC,
    unsigned int* __restrict__ ghist,
    unsigned int* __restrict__ cnt)
{
    const int lane = threadIdx.x & 63;
    const int wid  = threadIdx.x >> 6;
    __shared__ unsigned long long wred[FPST/64];
    __shared__ int s_cur;

    if (k == 0){
        int gi = blockIdx.x*FPST + threadIdx.x;
        if (gi < MCENT*NBINS) ghist[gi] = 0u;
        if (gi < MCENT) cnt[gi] = 0u;
    }

    int cur = 0;
    if (k > 0){
        unsigned long long pb = 0ULL;
        for (int i = threadIdx.x; i < FPSB; i += FPST){
            unsigned long long v = partials[(k-1)*FPSB + i];
            if (v > pb) pb = v;
        }
#pragma unroll
        for (int off = 32; off > 0; off >>= 1){
            unsigned long long o = __shfl_xor(pb, off, 64);
            if (o > pb) pb = o;
        }
        if (lane == 0) wred[wid] = pb;
        __syncthreads();
        if (threadIdx.x == 0){
            unsigned long long b = wred[0];
#pragma unroll
            for (int w = 1; w < FPST/64; ++w) if (wred[w] > b) b = wred[w];
            s_cur = (int)(0xFFFFFFFFu - (unsigned)(b & 0xFFFFFFFFu));
        }
        __syncthreads();
        cur = s_cur;
    }

    if (blockIdx.x == 0 && threadIdx.x == 0){
        float cx = P[2*cur], cy = P[2*cur+1];
        cxy[2*k] = cx; cxy[2*k+1] = cy;
        outC[2*k] = cx; outC[2*k+1] = cy;
    }
    if (k >= MCENT-1) return;

    const float cx = P[2*cur], cy = P[2*cur+1];
    unsigned long long bk = 0ULL;
    const int T  = gridDim.x * FPST;
    const int NP = N >> 1;
    for (int q = blockIdx.x*FPST + threadIdx.x; q < NP; q += T){
        float4 p = ((const float4*)P)[q];           // (x0,y0,x1,y1)
        // match np: (dx*dx) + (dy*dy), no fma contraction; min is exact
        float dx0 = __fsub_rn(p.x, cx), dy0 = __fsub_rn(p.y, cy);
        float d0  = __fadd_rn(__fmul_rn(dx0,dx0), __fmul_rn(dy0,dy0));
        float dx1 = __fsub_rn(p.z, cx), dy1 = __fsub_rn(p.w, cy);
        float d1  = __fadd_rn(__fmul_rn(dx1,dx1), __fmul_rn(dy1,dy1));
        float2 mp;
        if (k == 0){ mp.x = d0; mp.y = d1; }
        else {
            mp = ((const float2*)min_d)[q];
            mp.x = fminf(mp.x, d0); mp.y = fminf(mp.y, d1);
        }
        ((float2*)min_d)[q] = mp;
        int g = 2*q;
        // max over min_d, tie -> lowest index (np argmax picks first); min_d >= 0
        unsigned long long k0 =
            ((unsigned long long)__float_as_uint(mp.x) << 32)
            | (unsigned long long)(0xFFFFFFFFu - (unsigned)g);
        unsigned long long k1 =
            ((unsigned long long)__float_as_uint(mp.y) << 32)
            | (unsigned long long)(0xFFFFFFFFu - (unsigned)(g+1));
        if (k0 > bk) bk = k0;
        if (k1 > bk) bk = k1;
    }
    if ((N & 1) && blockIdx.x == 0 && threadIdx.x == 0){
        int g = N-1;
        float dx = __fsub_rn(P[2*g], cx), dy = __fsub_rn(P[2*g+1], cy);
        float d  = __fadd_rn(__fmul_rn(dx,dx), __fmul_rn(dy,dy));
        float nm = (k == 0) ? d : fminf(min_d[g], d);
        min_d[g] = nm;
        unsigned long long kk =
            ((unsigned long long)__float_as_uint(nm) << 32)
            | (unsigned long long)(0xFFFFFFFFu - (unsigned)g);
        if (kk > bk) bk = kk;
    }
#pragma unroll
    for (int off = 32; off > 0; off >>= 1){
        unsigned long long o = __shfl_xor(bk, off, 64);
        if (o > bk) bk = o;
    }
    if (lane == 0) wred[wid] = bk;
    __syncthreads();
    if (threadIdx.x == 0){
        unsigned long long b = wred[0];
#pragma unroll
        for (int w = 1; w < FPST/64; ++w) if (wred[w] > b) b = wred[w];
        partials[k*FPSB + blockIdx.x] = b;
    }
}

// ---------------- kNN pass 1: SAMPLED exponent histogram (1/16 of points) ----------------
// Threshold from a subsample is a valid upper bound: the 64 sample points below
// thr are also in the full set (identical rounding), so >=64 full points pass;
// expected collected count ~= 64*16*1.5 ~= 1.5K << CAP.
__global__ __launch_bounds__(256) void hist_kernel(
    const float* __restrict__ P, int N,
    const float* __restrict__ cxy,
    unsigned int* __restrict__ ghist)
{
    __shared__ unsigned int h[MCENT*NBINS];
    __shared__ float scx[MCENT], scy[MCENT], scs2[MCENT];
    for (int i = threadIdx.x; i < MCENT*NBINS; i += blockDim.x) h[i] = 0u;
    if (threadIdx.x < MCENT){
        float a = cxy[2*threadIdx.x], b = cxy[2*threadIdx.x+1];
        scx[threadIdx.x] = a; scy[threadIdx.x] = b;
        scs2[threadIdx.x] = __fadd_rn(__fmul_rn(a,a), __fmul_rn(b,b));
    }
    __syncthreads();
    const int T    = gridDim.x * blockDim.x;
    const int NP16 = (N >> 1) >> 4;     // every 16th float4-pair
    for (int q = blockIdx.x*blockDim.x + threadIdx.x; q < NP16; q += T){
        float4 p = ((const float4*)P)[(size_t)q << 4];
        float ps20 = __fadd_rn(__fmul_rn(p.x,p.x), __fmul_rn(p.y,p.y));
        float ps21 = __fadd_rn(__fmul_rn(p.z,p.z), __fmul_rn(p.w,p.w));
#pragma unroll
        for (int m = 0; m < MCENT; ++m){
            // match reference expanded form: ps2 - 2*dot + cs2
            float dot0 = __fadd_rn(__fmul_rn(scx[m],p.x), __fmul_rn(scy[m],p.y));
            float d20  = __fadd_rn(__fsub_rn(ps20, __fmul_rn(2.0f,dot0)), scs2[m]);
            atomicAdd(&h[m*NBINS + (__float_as_uint(fmaxf(d20,0.0f)) >> 22)], 1u);
            float dot1 = __fadd_rn(__fmul_rn(scx[m],p.z), __fmul_rn(scy[m],p.w));
            float d21  = __fadd_rn(__fsub_rn(ps21, __fmul_rn(2.0f,dot1)), scs2[m]);
            atomicAdd(&h[m*NBINS + (__float_as_uint(fmaxf(d21,0.0f)) >> 22)], 1u);
        }
    }
    __syncthreads();
    for (int i = threadIdx.x; i < MCENT*NBINS; i += blockDim.x){
        unsigned v = h[i];
        if (v) atomicAdd(&ghist[i], v);
    }
}

__global__ void thr_kernel(const unsigned int* __restrict__ ghist,
                           float* __restrict__ thr){
    int m = threadIdx.x;
    if (m < MCENT){
        unsigned cum = 0; int B = NBINS-1;
        for (int b = 0; b < NBINS; ++b){
            cum += ghist[m*NBINS + b];
            if (cum >= KNN){ B = b; break; }
        }
        thr[m] = __uint_as_float((unsigned)(B+1) << 22);  // all bins <= B pass strictly
    }
}

// ---------------- kNN pass 2: collect candidates below threshold (2 pts/thread) ----------------
__global__ __launch_bounds__(256) void collect_kernel(
    const float* __restrict__ P, int N,
    const float* __restrict__ cxy,
    const float* __restrict__ thr,
    unsigned int* __restrict__ cnt,
    float* __restrict__ cd2,
    int* __restrict__ cidx)
{
    __shared__ float scx[MCENT], scy[MCENT], scs2[MCENT], sth[MCENT];
    if (threadIdx.x < MCENT){
        float a = cxy[2*threadIdx.x], b = cxy[2*threadIdx.x+1];
        scx[threadIdx.x]=a; scy[threadIdx.x]=b;
        scs2[threadIdx.x]=__fadd_rn(__fmul_rn(a,a),__fmul_rn(b,b));
        sth[threadIdx.x]=thr[threadIdx.x];
    }
    __syncthreads();
    const int T  = gridDim.x*blockDim.x;
    const int NP = N >> 1;
    for (int q = blockIdx.x*blockDim.x + threadIdx.x; q < NP; q += T){
        float4 p = ((const float4*)P)[q];
        float ps20 = __fadd_rn(__fmul_rn(p.x,p.x), __fmul_rn(p.y,p.y));
        float ps21 = __fadd_rn(__fmul_rn(p.z,p.z), __fmul_rn(p.w,p.w));
        int g = 2*q;
#pragma unroll
        for (int m = 0; m < MCENT; ++m){
            float dot0 = __fadd_rn(__fmul_rn(scx[m],p.x), __fmul_rn(scy[m],p.y));
            float d20  = __fadd_rn(__fsub_rn(ps20, __fmul_rn(2.0f,dot0)), scs2[m]);
            if (fmaxf(d20,0.0f) < sth[m]){
                unsigned pos = atomicAdd(&cnt[m], 1u);
                if (pos < CAP){ cd2[m*CAP+pos]=d20; cidx[m*CAP+pos]=g; }
            }
            float dot1 = __fadd_rn(__fmul_rn(scx[m],p.z), __fmul_rn(scy[m],p.w));
            float d21  = __fadd_rn(__fsub_rn(ps21, __fmul_rn(2.0f,dot1)), scs2[m]);
            if (fmaxf(d21,0.0f) < sth[m]){
                unsigned pos = atomicAdd(&cnt[m], 1u);
                if (pos < CAP){ cd2[m*CAP+pos]=d21; cidx[m*CAP+pos]=g+1; }
            }
        }
    }
    if ((N & 1) && blockIdx.x == 0 && threadIdx.x == 0){
        int g = N-1;
        float x = P[2*g], y = P[2*g+1];
        float ps2 = __fadd_rn(__fmul_rn(x,x), __fmul_rn(y,y));
        for (int m = 0; m < MCENT; ++m){
            float dot = __fadd_rn(__fmul_rn(scx[m],x), __fmul_rn(scy[m],y));
            float d2  = __fadd_rn(__fsub_rn(ps2, __fmul_rn(2.0f,dot)), scs2[m]);
            if (fmaxf(d2,0.0f) < sth[m]){
                unsigned pos = atomicAdd(&cnt[m], 1u);
                if (pos < CAP){ cd2[m*CAP+pos]=d2; cidx[m*CAP+pos]=g; }
            }
        }
    }
}

// ---------------- exact top-64: linear refine hist -> finalists -> rank ----------------
// Refine bins are monotone in d2, so the finalist set (bins <= B2) is downward-
// closed: every non-finalist has strictly larger d2, hence strictly larger key.
// Ranks among finalists == global ranks. Fallback path is exact if FCAP overflows.
__global__ __launch_bounds__(256) void select_kernel(
    const unsigned int* __restrict__ cnt,
    const float* __restrict__ cd2,
    const int* __restrict__ cidx,
    const float* __restrict__ thr,
    int* __restrict__ nbr)
{
    const int m = blockIdx.x;
    __shared__ unsigned hh[512];
    __shared__ unsigned long long fkeys[FCAP];
    __shared__ unsigned fcnt;
    __shared__ int sB2;
    unsigned c = cnt[m]; if (c > CAP) c = CAP;
    const float s512 = 512.0f / thr[m];
    for (int i = threadIdx.x; i < 512; i += 256) hh[i] = 0u;
    if (threadIdx.x == 0) fcnt = 0u;
    __syncthreads();
    for (int i = threadIdx.x; i < (int)c; i += 256){
        int b = (int)(fmaxf(cd2[m*CAP+i], 0.0f) * s512);
        if (b > 511) b = 511;
        atomicAdd(&hh[b], 1u);
    }
    __syncthreads();
    if (threadIdx.x == 0){
        unsigned cum = 0; int B = 511;
        for (int b = 0; b < 512; ++b){ cum += hh[b]; if (cum >= KNN){ B = b; break; } }
        sB2 = B;
    }
    __syncthreads();
    const int B2 = sB2;
    for (int i = threadIdx.x; i < (int)c; i += 256){
        float d2 = cd2[m*CAP+i];
        int b = (int)(fmaxf(d2, 0.0f) * s512);
        if (b > 511) b = 511;
        if (b <= B2){
            unsigned pos = atomicAdd(&fcnt, 1u);
            if (pos < FCAP){
                unsigned u = __float_as_uint(d2);
                u = (u & 0x80000000u) ? ~u : (u | 0x80000000u);  // float -> sortable
                fkeys[pos] = ((unsigned long long)u << 32)
                           | (unsigned long long)(unsigned)cidx[m*CAP+i]; // tie -> lower idx
            }
        }
    }
    __syncthreads();
    unsigned f = fcnt;
    if (f <= FCAP){
        for (int i = threadIdx.x; i < (int)f; i += 256){
            unsigned long long ki = fkeys[i];
            int rank = 0;
            for (int j = 0; j < (int)f; ++j) rank += (fkeys[j] < ki);
            if (rank < KNN) nbr[m*KNN + rank] = (int)(unsigned)(ki & 0xFFFFFFFFu);
        }
    } else {
        // exact O(c^2) fallback from global memory (not expected to execute)
        for (int i = threadIdx.x; i < (int)c; i += 256){
            unsigned ui = __float_as_uint(cd2[m*CAP+i]);
            ui = (ui & 0x80000000u) ? ~ui : (ui | 0x80000000u);
            unsigned long long ki = ((unsigned long long)ui << 32)
                                  | (unsigned long long)(unsigned)cidx[m*CAP+i];
            int rank = 0;
            for (int j = 0; j < (int)c; ++j){
                unsigned uj = __float_as_uint(cd2[m*CAP+j]);
                uj = (uj & 0x80000000u) ? ~uj : (uj | 0x80000000u);
                unsigned long long kj = ((unsigned long long)uj << 32)
                                      | (unsigned long long)(unsigned)cidx[m*CAP+j];
                rank += (kj < ki);
            }
            if (rank < KNN) nbr[m*KNN + rank] = (int)(unsigned)(ki & 0xFFFFFFFFu);
        }
    }
}

// ---------------- features + MLP + pooling + head: 1024 threads/center ----------------
__global__ __launch_bounds__(MLPT) void mlp_kernel(
    const float* __restrict__ P,
    const float* __restrict__ cxy,
    const int* __restrict__ nbr,
    const float* __restrict__ W1, const float* __restrict__ b1,
    const float* __restrict__ W2, const float* __restrict__ b2,
    const float* __restrict__ W3, const float* __restrict__ b3,
    const float* __restrict__ W4, const float* __restrict__ b4,
    float* __restrict__ outF)
{
    const int m = blockIdx.x;
    const int tid = threadIdx.x;
    __shared__ float feat[KNN][32];          // 8 KB (29 padded to 32)
    __shared__ float h1s[KNN][64];           // 16 KB
    __shared__ float sW1[29*64];             // 7.4 KB
    __shared__ float sW2[64*128];            // 32 KB
    __shared__ float pmax[8][128], psum[8][128]; // 8 KB
    __shared__ float z[260];
    __shared__ float part[8][128];           // 4 KB
    __shared__ float zz[128];

    // stage W2 (8192 f) and W1 (1856 f) with float4, all issued up front
    {
        const float4* s2 = (const float4*)W2;
        float4* d2 = (float4*)sW2;
        d2[tid]        = s2[tid];
        d2[tid + 1024] = s2[tid + 1024];
        if (tid < 464) ((float4*)sW1)[tid] = ((const float4*)W1)[tid];
    }

    const float cx = cxy[2*m], cy = cxy[2*m+1];
    if (tid < KNN){
        int g = nbr[m*KNN + tid];
        float dx = P[2*g]   - cx;
        float dy = P[2*g+1] - cy;
        float r  = sqrtf(dx*dx + dy*dy);
        float th = atan2f(dy, dx);
        feat[tid][0]=dx; feat[tid][1]=dy; feat[tid][2]=r;
        feat[tid][3]=sinf(th); feat[tid][4]=cosf(th);
        float fx = dx, fy = dy;      // freqs 1,2,4,8,16,32
#pragma unroll
        for (int l = 0; l < 6; ++l){
            feat[tid][5+4*l+0]=sinf(fx);
            feat[tid][5+4*l+1]=sinf(fy);
            feat[tid][5+4*l+2]=cosf(fx);
            feat[tid][5+4*l+3]=cosf(fy);
            fx += fx; fy += fy;
        }
    }
    __syncthreads();

    // h1 = gelu(per_pt @ W1 + b1): 64x64 outputs, 4 per thread
#pragma unroll
    for (int rep = 0; rep < 4; ++rep){
        int o = rep*MLPT + tid;
        int k = o >> 6, j = o & 63;
        float acc = b1[j];
#pragma unroll
        for (int c = 0; c < 29; ++c) acc += feat[k][c] * sW1[c*64 + j];
        h1s[k][j] = gelu_f(acc);
    }
    __syncthreads();

    // h2 = gelu(h1 @ W2 + b2) with fused max/mean pooling: 8 k's per thread
    {
        int j = tid & 127, kh = tid >> 7;
        float lmax = -3.402823466e+38f, lsum = 0.f;
        for (int kk = 0; kk < 8; ++kk){
            int k = kh*8 + kk;
            float acc = b2[j];
#pragma unroll 8
            for (int i = 0; i < 64; ++i) acc += h1s[k][i] * sW2[i*128 + j];
            float v = gelu_f(acc);
            lmax = fmaxf(lmax, v);
            lsum += v;
        }
        pmax[kh][j] = lmax; psum[kh][j] = lsum;
    }
    __syncthreads();
    if (tid < 128){
        float mx = pmax[0][tid], sm = psum[0][tid];
#pragma unroll
        for (int w = 1; w < 8; ++w){ mx = fmaxf(mx, pmax[w][tid]); sm += psum[w][tid]; }
        z[tid]       = mx;
        z[128 + tid] = sm * (1.0f/64.0f);
    }
    if (tid >= 128 && tid < 192){   // r stats on wave 2
        int l = tid - 128;
        float r = feat[l][2];
        float s = r, mx = r, mn = r;
        for (int off = 1; off < 64; off <<= 1){
            s  += __shfl_xor(s, off, 64);
            mx  = fmaxf(mx, __shfl_xor(mx, off, 64));
            mn  = fminf(mn, __shfl_xor(mn, off, 64));
        }
        float mean = s * (1.0f/64.0f);
        float dv = (r-mean)*(r-mean);
        for (int off = 1; off < 64; off <<= 1) dv += __shfl_xor(dv, off, 64);
        if (l == 0){
            z[256]=mean; z[257]=mx; z[258]=mn; z[259]=sqrtf(dv*(1.0f/63.0f));
        }
    }
    __syncthreads();

    // head: gelu(z @ W3 + b3) @ W4 + b4, reduction split 8 ways
    {
        int j = tid & 127, seg = tid >> 7;
        int i0  = (seg < 4) ? seg*33 : 132 + (seg-4)*32;
        int cntn = (seg < 4) ? 33 : 32;
        float acc = 0.f;
        for (int i = i0; i < i0 + cntn; ++i) acc += z[i]*W3[i*128+j];
        part[seg][j] = acc;
    }
    __syncthreads();
    if (tid < 128){
        float a = part[0][tid];
#pragma unroll
        for (int w = 1; w < 8; ++w) a += part[w][tid];
        zz[tid] = gelu_f(a + b3[tid]);
    }
    __syncthreads();
    {
        int j = tid & 127, seg = tid >> 7;
        float acc = 0.f;
#pragma unroll
        for (int i = seg*16; i < seg*16+16; ++i) acc += zz[i]*W4[i*128+j];
        part[seg][j] = acc;
    }
    __syncthreads();
    if (tid < 128){
        float a = part[0][tid];
#pragma unroll
        for (int w = 1; w < 8; ++w) a += part[w][tid];
        outF[m*128 + tid] = a + b4[tid];
    }
}

extern "C" void kernel_launch(void* const* d_in, const int* in_sizes, int n_in,
                              void* d_out, int out_size, void* d_ws, size_t ws_size,
                              hipStream_t stream)
{
    const float* P  = (const float*)d_in[0];
    const float* W1 = (const float*)d_in[1];
    const float* b1 = (const float*)d_in[2];
    const float* W2 = (const float*)d_in[3];
    const float* b2 = (const float*)d_in[4];
    const float* W3 = (const float*)d_in[5];
    const float* b3 = (const float*)d_in[6];
    const float* W4 = (const float*)d_in[7];
    const float* b4 = (const float*)d_in[8];
    int N = in_sizes[0] / 2;
    float* outF = (float*)d_out;               // [16][128]
    float* outC = outF + MCENT*128;            // [16][2]
    (void)n_in; (void)out_size; (void)ws_size;

    char* base = (char*)d_ws;
    size_t off = 0;
    auto take = [&](size_t bytes)->char*{
        char* p = base + off;
        off = (off + bytes + 255) & ~(size_t)255;
        return p;
    };
    unsigned long long* partials = (unsigned long long*)take((size_t)MCENT*FPSB*8);
    float* cxy         = (float*)take(MCENT*2*4);
    unsigned int* ghist= (unsigned int*)take(MCENT*NBINS*4);
    unsigned int* cnt  = (unsigned int*)take(MCENT*4);
    float* thr         = (float*)take(MCENT*4);
    int*   nbr         = (int*)  take(MCENT*KNN*4);
    float* cd2         = (float*)take((size_t)MCENT*CAP*4);
    int*   cidx        = (int*)  take((size_t)MCENT*CAP*4);
    float* min_d       = (float*)take((size_t)N*4);

    // FPS: 16 plain launches; kernel boundaries are the grid-wide sync.
    // k=0 also zero-inits ghist/cnt.
    for (int k = 0; k < MCENT-1; ++k)
        fps_step<<<FPSB, FPST, 0, stream>>>(P, N, min_d, partials, k, cxy, outC,
                                            ghist, cnt);
    fps_step<<<1, FPST, 0, stream>>>(P, N, min_d, partials, MCENT-1, cxy, outC,
                                     ghist, cnt);

    hist_kernel<<<128, 256, 0, stream>>>(P, N, cxy, ghist);
    thr_kernel<<<1, 64, 0, stream>>>(ghist, thr);
    collect_kernel<<<512, 256, 0, stream>>>(P, N, cxy, thr, cnt, cd2, cidx);
    select_kernel<<<MCENT, 256, 0, stream>>>(cnt, cd2, cidx, thr, nbr);
    mlp_kernel<<<MCENT, MLPT, 0, stream>>>(P, cxy, nbr, W1,b1,W2,b2,W3,b3,W4,b4, outF);
}

// Round 10
// 312.500 us; speedup vs baseline: 1.8178x; 1.8178x over previous
//
#include <hip/hip_runtime.h>
#include <math.h>

#define MCENT 16
#define KNN   64
#define NBINS 512
#define RBINS 256
#define CAP   7936
#define FPSB  512
#define FPST  256
#define MLPT  1024

__device__ __forceinline__ float gelu_f(float x){
    return 0.5f * x * (1.0f + erff(x * 0.70710678118654752440f));
}

// ---------------- FPS step k: no device-side grid sync, 16 graph launches ----------------
__global__ __launch_bounds__(FPST) void fps_step(
    const float* __restrict__ P, int N,
    float* __restrict__ min_d,                  // [N] in ws, persists across steps
    unsigned long long* __restrict__ partials,  // [MCENT][FPSB]
    int k,
    float* __restrict__ cxy,
    float* __restrict__ outC,
    unsigned int* __restrict__ ghist,
    unsigned int* __restrict__ cnt)
{
    const int lane = threadIdx.x & 63;
    const int wid  = threadIdx.x >> 6;
    __shared__ unsigned long long wred[FPST/64];
    __shared__ int s_cur;

    if (k == 0){
        int gi = blockIdx.x*FPST + threadIdx.x;
        if (gi < MCENT*NBINS) ghist[gi] = 0u;
        if (gi < MCENT) cnt[gi] = 0u;
    }

    int cur = 0;
    if (k > 0){
        unsigned long long pb = 0ULL;
        for (int i = threadIdx.x; i < FPSB; i += FPST){
            unsigned long long v = partials[(k-1)*FPSB + i];
            if (v > pb) pb = v;
        }
#pragma unroll
        for (int off = 32; off > 0; off >>= 1){
            unsigned long long o = __shfl_xor(pb, off, 64);
            if (o > pb) pb = o;
        }
        if (lane == 0) wred[wid] = pb;
        __syncthreads();
        if (threadIdx.x == 0){
            unsigned long long b = wred[0];
#pragma unroll
            for (int w = 1; w < FPST/64; ++w) if (wred[w] > b) b = wred[w];
            s_cur = (int)(0xFFFFFFFFu - (unsigned)(b & 0xFFFFFFFFu));
        }
        __syncthreads();
        cur = s_cur;
    }

    if (blockIdx.x == 0 && threadIdx.x == 0){
        float cx = P[2*cur], cy = P[2*cur+1];
        cxy[2*k] = cx; cxy[2*k+1] = cy;
        outC[2*k] = cx; outC[2*k+1] = cy;
    }
    if (k >= MCENT-1) return;

    const float cx = P[2*cur], cy = P[2*cur+1];
    unsigned long long bk = 0ULL;
    const int T  = gridDim.x * FPST;
    const int NP = N >> 1;
    for (int q = blockIdx.x*FPST + threadIdx.x; q < NP; q += T){
        float4 p = ((const float4*)P)[q];           // (x0,y0,x1,y1)
        // match np: (dx*dx) + (dy*dy), no fma contraction; min is exact
        float dx0 = __fsub_rn(p.x, cx), dy0 = __fsub_rn(p.y, cy);
        float d0  = __fadd_rn(__fmul_rn(dx0,dx0), __fmul_rn(dy0,dy0));
        float dx1 = __fsub_rn(p.z, cx), dy1 = __fsub_rn(p.w, cy);
        float d1  = __fadd_rn(__fmul_rn(dx1,dx1), __fmul_rn(dy1,dy1));
        float2 mp;
        if (k == 0){ mp.x = d0; mp.y = d1; }
        else {
            mp = ((const float2*)min_d)[q];
            mp.x = fminf(mp.x, d0); mp.y = fminf(mp.y, d1);
        }
        ((float2*)min_d)[q] = mp;
        int g = 2*q;
        // max over min_d, tie -> lowest index (np argmax picks first); min_d >= 0
        unsigned long long k0 =
            ((unsigned long long)__float_as_uint(mp.x) << 32)
            | (unsigned long long)(0xFFFFFFFFu - (unsigned)g);
        unsigned long long k1 =
            ((unsigned long long)__float_as_uint(mp.y) << 32)
            | (unsigned long long)(0xFFFFFFFFu - (unsigned)(g+1));
        if (k0 > bk) bk = k0;
        if (k1 > bk) bk = k1;
    }
    if ((N & 1) && blockIdx.x == 0 && threadIdx.x == 0){
        int g = N-1;
        float dx = __fsub_rn(P[2*g], cx), dy = __fsub_rn(P[2*g+1], cy);
        float d  = __fadd_rn(__fmul_rn(dx,dx), __fmul_rn(dy,dy));
        float nm = (k == 0) ? d : fminf(min_d[g], d);
        min_d[g] = nm;
        unsigned long long kk =
            ((unsigned long long)__float_as_uint(nm) << 32)
            | (unsigned long long)(0xFFFFFFFFu - (unsigned)g);
        if (kk > bk) bk = kk;
    }
#pragma unroll
    for (int off = 32; off > 0; off >>= 1){
        unsigned long long o = __shfl_xor(bk, off, 64);
        if (o > bk) bk = o;
    }
    if (lane == 0) wred[wid] = bk;
    __syncthreads();
    if (threadIdx.x == 0){
        unsigned long long b = wred[0];
#pragma unroll
        for (int w = 1; w < FPST/64; ++w) if (wred[w] > b) b = wred[w];
        partials[k*FPSB + blockIdx.x] = b;
    }
}

// ---------------- kNN pass 1: SAMPLED exponent histogram (1/16 of points) ----------------
// Also zero-inits rhist (stream-ordered before refine_kernel).
__global__ __launch_bounds__(256) void hist_kernel(
    const float* __restrict__ P, int N,
    const float* __restrict__ cxy,
    unsigned int* __restrict__ ghist,
    unsigned int* __restrict__ rhist)
{
    __shared__ unsigned int h[MCENT*NBINS];
    __shared__ float scx[MCENT], scy[MCENT], scs2[MCENT];
    {
        int gi = blockIdx.x*blockDim.x + threadIdx.x;
        if (gi < MCENT*RBINS) rhist[gi] = 0u;
    }
    for (int i = threadIdx.x; i < MCENT*NBINS; i += blockDim.x) h[i] = 0u;
    if (threadIdx.x < MCENT){
        float a = cxy[2*threadIdx.x], b = cxy[2*threadIdx.x+1];
        scx[threadIdx.x] = a; scy[threadIdx.x] = b;
        scs2[threadIdx.x] = __fadd_rn(__fmul_rn(a,a), __fmul_rn(b,b));
    }
    __syncthreads();
    const int T    = gridDim.x * blockDim.x;
    const int NP16 = (N >> 1) >> 4;     // every 16th float4-pair
    for (int q = blockIdx.x*blockDim.x + threadIdx.x; q < NP16; q += T){
        float4 p = ((const float4*)P)[(size_t)q << 4];
        float ps20 = __fadd_rn(__fmul_rn(p.x,p.x), __fmul_rn(p.y,p.y));
        float ps21 = __fadd_rn(__fmul_rn(p.z,p.z), __fmul_rn(p.w,p.w));
#pragma unroll
        for (int m = 0; m < MCENT; ++m){
            // match reference expanded form: ps2 - 2*dot + cs2
            float dot0 = __fadd_rn(__fmul_rn(scx[m],p.x), __fmul_rn(scy[m],p.y));
            float d20  = __fadd_rn(__fsub_rn(ps20, __fmul_rn(2.0f,dot0)), scs2[m]);
            atomicAdd(&h[m*NBINS + (__float_as_uint(fmaxf(d20,0.0f)) >> 22)], 1u);
            float dot1 = __fadd_rn(__fmul_rn(scx[m],p.z), __fmul_rn(scy[m],p.w));
            float d21  = __fadd_rn(__fsub_rn(ps21, __fmul_rn(2.0f,dot1)), scs2[m]);
            atomicAdd(&h[m*NBINS + (__float_as_uint(fmaxf(d21,0.0f)) >> 22)], 1u);
        }
    }
    __syncthreads();
    for (int i = threadIdx.x; i < MCENT*NBINS; i += blockDim.x){
        unsigned v = h[i];
        if (v) atomicAdd(&ghist[i], v);
    }
}

// Coarse threshold from sampled hist; >=64 full points lie strictly below thrc
// (the 64 sampled ones are full points; identical __f*_rn rounding).
__global__ void thr_kernel(const unsigned int* __restrict__ ghist,
                           float* __restrict__ thr,
                           float* __restrict__ sc2){
    int m = threadIdx.x;
    if (m < MCENT){
        unsigned cum = 0; int B = NBINS-1;
        for (int b = 0; b < NBINS; ++b){
            cum += ghist[m*NBINS + b];
            if (cum >= KNN){ B = b; break; }
        }
        float t = __uint_as_float((unsigned)(B+1) << 22);
        thr[m] = t;
        sc2[m] = 255.0f / t;   // single source: refine & collect use identical bits
    }
}

// ---------------- refine: full-N linear histogram within [0, thrc) ----------------
// Only ~1.5K points/center fall below thrc -> LDS atomics are sparse (no
// serialization, unlike a dense full-N histogram). bin identical to collect's.
__global__ __launch_bounds__(256) void refine_kernel(
    const float* __restrict__ P, int N,
    const float* __restrict__ cxy,
    const float* __restrict__ sc2,
    unsigned int* __restrict__ rhist)
{
    __shared__ unsigned int h[MCENT*RBINS];
    __shared__ float scx[MCENT], scy[MCENT], scs2[MCENT], ssc[MCENT];
    for (int i = threadIdx.x; i < MCENT*RBINS; i += blockDim.x) h[i] = 0u;
    if (threadIdx.x < MCENT){
        float a = cxy[2*threadIdx.x], b = cxy[2*threadIdx.x+1];
        scx[threadIdx.x]=a; scy[threadIdx.x]=b;
        scs2[threadIdx.x]=__fadd_rn(__fmul_rn(a,a),__fmul_rn(b,b));
        ssc[threadIdx.x]=sc2[threadIdx.x];
    }
    __syncthreads();
    const int T  = gridDim.x * blockDim.x;
    const int NP = N >> 1;
    for (int q = blockIdx.x*blockDim.x + threadIdx.x; q < NP; q += T){
        float4 p = ((const float4*)P)[q];
        float ps20 = __fadd_rn(__fmul_rn(p.x,p.x), __fmul_rn(p.y,p.y));
        float ps21 = __fadd_rn(__fmul_rn(p.z,p.z), __fmul_rn(p.w,p.w));
#pragma unroll
        for (int m = 0; m < MCENT; ++m){
            float dot0 = __fadd_rn(__fmul_rn(scx[m],p.x), __fmul_rn(scy[m],p.y));
            float d20  = __fadd_rn(__fsub_rn(ps20, __fmul_rn(2.0f,dot0)), scs2[m]);
            int b0 = (int)(fmaxf(d20, 0.0f) * ssc[m]);
            if (b0 < RBINS) atomicAdd(&h[m*RBINS + b0], 1u);
            float dot1 = __fadd_rn(__fmul_rn(scx[m],p.z), __fmul_rn(scy[m],p.w));
            float d21  = __fadd_rn(__fsub_rn(ps21, __fmul_rn(2.0f,dot1)), scs2[m]);
            int b1 = (int)(fmaxf(d21, 0.0f) * ssc[m]);
            if (b1 < RBINS) atomicAdd(&h[m*RBINS + b1], 1u);
        }
    }
    if ((N & 1) && blockIdx.x == 0 && threadIdx.x == 0){
        int g = N-1;
        float x = P[2*g], y = P[2*g+1];
        float ps2 = __fadd_rn(__fmul_rn(x,x), __fmul_rn(y,y));
        for (int m = 0; m < MCENT; ++m){
            float dot = __fadd_rn(__fmul_rn(scx[m],x), __fmul_rn(scy[m],y));
            float d2  = __fadd_rn(__fsub_rn(ps2, __fmul_rn(2.0f,dot)), scs2[m]);
            int b = (int)(fmaxf(d2, 0.0f) * ssc[m]);
            if (b < RBINS) atomicAdd(&h[m*RBINS + b], 1u);
        }
    }
    __syncthreads();
    for (int i = threadIdx.x; i < MCENT*RBINS; i += blockDim.x){
        unsigned v = h[i];
        if (v) atomicAdd(&rhist[i], v);
    }
}

// Tight bin bound: B2 = min b with cum >= 64. {d2c < thrc} maps to bins <= 255
// (255/256 slack >> float eps), so cum(0..255) >= 64 always -> B2 in [0,255].
__global__ void thr2_kernel(const unsigned int* __restrict__ rhist,
                            int* __restrict__ B2){
    int m = threadIdx.x;
    if (m < MCENT){
        unsigned cum = 0; int B = RBINS-1;
        for (int b = 0; b < RBINS; ++b){
            cum += rhist[m*RBINS + b];
            if (cum >= KNN){ B = b; break; }
        }
        B2[m] = B;
    }
}

// ---------------- kNN collect: bin(d2) <= B2 (~70 candidates/center) ----------------
// bin computed with the same float expr as refine -> identical membership.
// Downward-closed in d2 (floor(x*sc) monotone) -> superset of true top-64.
__global__ __launch_bounds__(256) void collect_kernel(
    const float* __restrict__ P, int N,
    const float* __restrict__ cxy,
    const float* __restrict__ sc2,
    const int* __restrict__ B2,
    unsigned int* __restrict__ cnt,
    float* __restrict__ cd2,
    int* __restrict__ cidx)
{
    __shared__ float scx[MCENT], scy[MCENT], scs2[MCENT], ssc[MCENT];
    __shared__ int sB2[MCENT];
    if (threadIdx.x < MCENT){
        float a = cxy[2*threadIdx.x], b = cxy[2*threadIdx.x+1];
        scx[threadIdx.x]=a; scy[threadIdx.x]=b;
        scs2[threadIdx.x]=__fadd_rn(__fmul_rn(a,a),__fmul_rn(b,b));
        ssc[threadIdx.x]=sc2[threadIdx.x];
        sB2[threadIdx.x]=B2[threadIdx.x];
    }
    __syncthreads();
    const int T  = gridDim.x*blockDim.x;
    const int NP = N >> 1;
    for (int q = blockIdx.x*blockDim.x + threadIdx.x; q < NP; q += T){
        float4 p = ((const float4*)P)[q];
        float ps20 = __fadd_rn(__fmul_rn(p.x,p.x), __fmul_rn(p.y,p.y));
        float ps21 = __fadd_rn(__fmul_rn(p.z,p.z), __fmul_rn(p.w,p.w));
        int g = 2*q;
#pragma unroll
        for (int m = 0; m < MCENT; ++m){
            float dot0 = __fadd_rn(__fmul_rn(scx[m],p.x), __fmul_rn(scy[m],p.y));
            float d20  = __fadd_rn(__fsub_rn(ps20, __fmul_rn(2.0f,dot0)), scs2[m]);
            if ((int)(fmaxf(d20,0.0f) * ssc[m]) <= sB2[m]){
                unsigned pos = atomicAdd(&cnt[m], 1u);
                if (pos < CAP){ cd2[m*CAP+pos]=d20; cidx[m*CAP+pos]=g; }
            }
            float dot1 = __fadd_rn(__fmul_rn(scx[m],p.z), __fmul_rn(scy[m],p.w));
            float d21  = __fadd_rn(__fsub_rn(ps21, __fmul_rn(2.0f,dot1)), scs2[m]);
            if ((int)(fmaxf(d21,0.0f) * ssc[m]) <= sB2[m]){
                unsigned pos = atomicAdd(&cnt[m], 1u);
                if (pos < CAP){ cd2[m*CAP+pos]=d21; cidx[m*CAP+pos]=g+1; }
            }
        }
    }
    if ((N & 1) && blockIdx.x == 0 && threadIdx.x == 0){
        int g = N-1;
        float x = P[2*g], y = P[2*g+1];
        float ps2 = __fadd_rn(__fmul_rn(x,x), __fmul_rn(y,y));
        for (int m = 0; m < MCENT; ++m){
            float dot = __fadd_rn(__fmul_rn(scx[m],x), __fmul_rn(scy[m],y));
            float d2  = __fadd_rn(__fsub_rn(ps2, __fmul_rn(2.0f,dot)), scs2[m]);
            if ((int)(fmaxf(d2,0.0f) * ssc[m]) <= sB2[m]){
                unsigned pos = atomicAdd(&cnt[m], 1u);
                if (pos < CAP){ cd2[m*CAP+pos]=d2; cidx[m*CAP+pos]=g; }
            }
        }
    }
}

// ---------------- exact top-64 per center: rank by pairwise comparison ----------------
__global__ __launch_bounds__(256) void select_kernel(
    const unsigned int* __restrict__ cnt,
    const float* __restrict__ cd2,
    const int* __restrict__ cidx,
    int* __restrict__ nbr)
{
    const int m = blockIdx.x;
    __shared__ unsigned long long keys[CAP];
    unsigned c = cnt[m]; if (c > CAP) c = CAP;
    for (int i = threadIdx.x; i < (int)c; i += 256){
        unsigned u = __float_as_uint(cd2[m*CAP+i]);
        u = (u & 0x80000000u) ? ~u : (u | 0x80000000u);  // float -> sortable uint
        keys[i] = ((unsigned long long)u << 32)
                | (unsigned long long)(unsigned)cidx[m*CAP+i]; // tie -> lower idx
    }
    __syncthreads();
    // each candidate's exact rank = #keys smaller; keys unique (idx in low bits)
    for (int i = threadIdx.x; i < (int)c; i += 256){
        unsigned long long ki = keys[i];
        int rank = 0;
        for (int j = 0; j < (int)c; ++j) rank += (keys[j] < ki);
        if (rank < KNN) nbr[m*KNN + rank] = (int)(unsigned)(ki & 0xFFFFFFFFu);
    }
}

// ---------------- features + MLP + pooling + head: 1024 threads/center ----------------
__global__ __launch_bounds__(MLPT) void mlp_kernel(
    const float* __restrict__ P,
    const float* __restrict__ cxy,
    const int* __restrict__ nbr,
    const float* __restrict__ W1, const float* __restrict__ b1,
    const float* __restrict__ W2, const float* __restrict__ b2,
    const float* __restrict__ W3, const float* __restrict__ b3,
    const float* __restrict__ W4, const float* __restrict__ b4,
    float* __restrict__ outF)
{
    const int m = blockIdx.x;
    const int tid = threadIdx.x;
    __shared__ float feat[KNN][32];          // 8 KB (29 padded to 32)
    __shared__ float h1s[KNN][64];           // 16 KB
    __shared__ float sW1[29*64];             // 7.4 KB
    __shared__ float sW2[64*128];            // 32 KB
    __shared__ float pmax[8][128], psum[8][128]; // 8 KB
    __shared__ float z[260];
    __shared__ float part[8][128];           // 4 KB
    __shared__ float zz[128];

    // stage W2 (8192 f) and W1 (1856 f) with float4, all issued up front
    {
        const float4* s2 = (const float4*)W2;
        float4* d2 = (float4*)sW2;
        d2[tid]        = s2[tid];
        d2[tid + 1024] = s2[tid + 1024];
        if (tid < 464) ((float4*)sW1)[tid] = ((const float4*)W1)[tid];
    }

    const float cx = cxy[2*m], cy = cxy[2*m+1];
    if (tid < KNN){
        int g = nbr[m*KNN + tid];
        float dx = P[2*g]   - cx;
        float dy = P[2*g+1] - cy;
        float r  = sqrtf(dx*dx + dy*dy);
        float th = atan2f(dy, dx);
        feat[tid][0]=dx; feat[tid][1]=dy; feat[tid][2]=r;
        feat[tid][3]=sinf(th); feat[tid][4]=cosf(th);
        float fx = dx, fy = dy;      // freqs 1,2,4,8,16,32
#pragma unroll
        for (int l = 0; l < 6; ++l){
            feat[tid][5+4*l+0]=sinf(fx);
            feat[tid][5+4*l+1]=sinf(fy);
            feat[tid][5+4*l+2]=cosf(fx);
            feat[tid][5+4*l+3]=cosf(fy);
            fx += fx; fy += fy;
        }
    }
    __syncthreads();

    // h1 = gelu(per_pt @ W1 + b1): 64x64 outputs, 4 per thread
#pragma unroll
    for (int rep = 0; rep < 4; ++rep){
        int o = rep*MLPT + tid;
        int k = o >> 6, j = o & 63;
        float acc = b1[j];
#pragma unroll
        for (int c = 0; c < 29; ++c) acc += feat[k][c] * sW1[c*64 + j];
        h1s[k][j] = gelu_f(acc);
    }
    __syncthreads();

    // h2 = gelu(h1 @ W2 + b2) with fused max/mean pooling: 8 k's per thread
    {
        int j = tid & 127, kh = tid >> 7;
        float lmax = -3.402823466e+38f, lsum = 0.f;
        for (int kk = 0; kk < 8; ++kk){
            int k = kh*8 + kk;
            float acc = b2[j];
#pragma unroll 8
            for (int i = 0; i < 64; ++i) acc += h1s[k][i] * sW2[i*128 + j];
            float v = gelu_f(acc);
            lmax = fmaxf(lmax, v);
            lsum += v;
        }
        pmax[kh][j] = lmax; psum[kh][j] = lsum;
    }
    __syncthreads();
    if (tid < 128){
        float mx = pmax[0][tid], sm = psum[0][tid];
#pragma unroll
        for (int w = 1; w < 8; ++w){ mx = fmaxf(mx, pmax[w][tid]); sm += psum[w][tid]; }
        z[tid]       = mx;
        z[128 + tid] = sm * (1.0f/64.0f);
    }
    if (tid >= 128 && tid < 192){   // r stats on wave 2
        int l = tid - 128;
        float r = feat[l][2];
        float s = r, mx = r, mn = r;
        for (int off = 1; off < 64; off <<= 1){
            s  += __shfl_xor(s, off, 64);
            mx  = fmaxf(mx, __shfl_xor(mx, off, 64));
            mn  = fminf(mn, __shfl_xor(mn, off, 64));
        }
        float mean = s * (1.0f/64.0f);
        float dv = (r-mean)*(r-mean);
        for (int off = 1; off < 64; off <<= 1) dv += __shfl_xor(dv, off, 64);
        if (l == 0){
            z[256]=mean; z[257]=mx; z[258]=mn; z[259]=sqrtf(dv*(1.0f/63.0f));
        }
    }
    __syncthreads();

    // head: gelu(z @ W3 + b3) @ W4 + b4, reduction split 8 ways
    {
        int j = tid & 127, seg = tid >> 7;
        int i0  = (seg < 4) ? seg*33 : 132 + (seg-4)*32;
        int cntn = (seg < 4) ? 33 : 32;
        float acc = 0.f;
        for (int i = i0; i < i0 + cntn; ++i) acc += z[i]*W3[i*128+j];
        part[seg][j] = acc;
    }
    __syncthreads();
    if (tid < 128){
        float a = part[0][tid];
#pragma unroll
        for (int w = 1; w < 8; ++w) a += part[w][tid];
        zz[tid] = gelu_f(a + b3[tid]);
    }
    __syncthreads();
    {
        int j = tid & 127, seg = tid >> 7;
        float acc = 0.f;
#pragma unroll
        for (int i = seg*16; i < seg*16+16; ++i) acc += zz[i]*W4[i*128+j];
        part[seg][j] = acc;
    }
    __syncthreads();
    if (tid < 128){
        float a = part[0][tid];
#pragma unroll
        for (int w = 1; w < 8; ++w) a += part[w][tid];
        outF[m*128 + tid] = a + b4[tid];
    }
}

extern "C" void kernel_launch(void* const* d_in, const int* in_sizes, int n_in,
                              void* d_out, int out_size, void* d_ws, size_t ws_size,
                              hipStream_t stream)
{
    const float* P  = (const float*)d_in[0];
    const float* W1 = (const float*)d_in[1];
    const float* b1 = (const float*)d_in[2];
    const float* W2 = (const float*)d_in[3];
    const float* b2 = (const float*)d_in[4];
    const float* W3 = (const float*)d_in[5];
    const float* b3 = (const float*)d_in[6];
    const float* W4 = (const float*)d_in[7];
    const float* b4 = (const float*)d_in[8];
    int N = in_sizes[0] / 2;
    float* outF = (float*)d_out;               // [16][128]
    float* outC = outF + MCENT*128;            // [16][2]
    (void)n_in; (void)out_size; (void)ws_size;

    char* base = (char*)d_ws;
    size_t off = 0;
    auto take = [&](size_t bytes)->char*{
        char* p = base + off;
        off = (off + bytes + 255) & ~(size_t)255;
        return p;
    };
    unsigned long long* partials = (unsigned long long*)take((size_t)MCENT*FPSB*8);
    float* cxy         = (float*)take(MCENT*2*4);
    unsigned int* ghist= (unsigned int*)take(MCENT*NBINS*4);
    unsigned int* rhist= (unsigned int*)take(MCENT*RBINS*4);
    unsigned int* cnt  = (unsigned int*)take(MCENT*4);
    float* thr         = (float*)take(MCENT*4);
    float* sc2         = (float*)take(MCENT*4);
    int*   B2          = (int*)  take(MCENT*4);
    int*   nbr         = (int*)  take(MCENT*KNN*4);
    float* cd2         = (float*)take((size_t)MCENT*CAP*4);
    int*   cidx        = (int*)  take((size_t)MCENT*CAP*4);
    float* min_d       = (float*)take((size_t)N*4);

    // FPS: 16 plain launches; kernel boundaries are the grid-wide sync.
    // k=0 also zero-inits ghist/cnt.
    for (int k = 0; k < MCENT-1; ++k)
        fps_step<<<FPSB, FPST, 0, stream>>>(P, N, min_d, partials, k, cxy, outC,
                                            ghist, cnt);
    fps_step<<<1, FPST, 0, stream>>>(P, N, min_d, partials, MCENT-1, cxy, outC,
                                     ghist, cnt);

    hist_kernel<<<128, 256, 0, stream>>>(P, N, cxy, ghist, rhist);
    thr_kernel<<<1, 64, 0, stream>>>(ghist, thr, sc2);
    refine_kernel<<<256, 256, 0, stream>>>(P, N, cxy, sc2, rhist);
    thr2_kernel<<<1, 64, 0, stream>>>(rhist, B2);
    collect_kernel<<<512, 256, 0, stream>>>(P, N, cxy, sc2, B2, cnt, cd2, cidx);
    select_kernel<<<MCENT, 256, 0, stream>>>(cnt, cd2, cidx, nbr);
    mlp_kernel<<<MCENT, MLPT, 0, stream>>>(P, cxy, nbr, W1,b1,W2,b2,W3,b3,W4,b4, outF);
}

// Round 11
// 310.431 us; speedup vs baseline: 1.8299x; 1.0067x over previous
//
#include <hip/hip_runtime.h>
#include <math.h>

#define MCENT 16
#define KNN   64
#define NBINS 512
#define RBINS 256
#define CAP   7936
#define FPSB  1024
#define FPST  256
#define MLPT  1024

__device__ __forceinline__ float gelu_f(float x){
    return 0.5f * x * (1.0f + erff(x * 0.70710678118654752440f));
}

// Contiguous 1/8 slice of [0,NP) per XCD (blockIdx%8 -> XCD round-robin
// heuristic; wrong mapping costs only locality, never correctness).
__device__ __forceinline__ void xcd_slice(int NP, int B, int bid, int tpb, int tid,
                                          int* q0, int* s1, int* step){
    int xcd = bid & 7, j = bid >> 3, Bx = B >> 3;
    long long np = NP;
    *q0   = (int)((np * xcd) >> 3) + j*tpb + tid;
    *s1   = (int)((np * (xcd+1)) >> 3);
    *step = Bx * tpb;
}

// ---------------- FPS step k (k=0..14): kernel boundary = grid sync ----------------
__global__ __launch_bounds__(FPST) void fps_step(
    const float* __restrict__ P, int N,
    float* __restrict__ min_d,
    unsigned long long* __restrict__ partials,  // [MCENT][FPSB]
    int k,
    float* __restrict__ cxy,
    float* __restrict__ outC,
    unsigned int* __restrict__ ghist,
    unsigned int* __restrict__ cnt)
{
    const int lane = threadIdx.x & 63;
    const int wid  = threadIdx.x >> 6;
    __shared__ unsigned long long wred[FPST/64];
    __shared__ int s_cur;

    if (k == 0){
        int gi = blockIdx.x*FPST + threadIdx.x;
        if (gi < MCENT*NBINS) ghist[gi] = 0u;
        if (gi < MCENT) cnt[gi] = 0u;
    }

    int cur = 0;
    if (k > 0){
        unsigned long long pb = 0ULL;
        for (int i = threadIdx.x; i < FPSB; i += FPST){
            unsigned long long v = partials[(k-1)*FPSB + i];
            if (v > pb) pb = v;
        }
#pragma unroll
        for (int off = 32; off > 0; off >>= 1){
            unsigned long long o = __shfl_xor(pb, off, 64);
            if (o > pb) pb = o;
        }
        if (lane == 0) wred[wid] = pb;
        __syncthreads();
        if (threadIdx.x == 0){
            unsigned long long b = wred[0];
#pragma unroll
            for (int w = 1; w < FPST/64; ++w) if (wred[w] > b) b = wred[w];
            s_cur = (int)(0xFFFFFFFFu - (unsigned)(b & 0xFFFFFFFFu));
        }
        __syncthreads();
        cur = s_cur;
    }

    if (blockIdx.x == 0 && threadIdx.x == 0){
        float cx = P[2*cur], cy = P[2*cur+1];
        cxy[2*k] = cx; cxy[2*k+1] = cy;
        outC[2*k] = cx; outC[2*k+1] = cy;
    }

    const float cx = P[2*cur], cy = P[2*cur+1];
    unsigned long long bk = 0ULL;
    const int NP = N >> 1;
    int q0, s1, st;
    xcd_slice(NP, gridDim.x, blockIdx.x, FPST, threadIdx.x, &q0, &s1, &st);
    for (int q = q0; q < s1; q += st){
        float4 p = ((const float4*)P)[q];           // (x0,y0,x1,y1)
        // match np: (dx*dx) + (dy*dy), no fma contraction; min is exact
        float dx0 = __fsub_rn(p.x, cx), dy0 = __fsub_rn(p.y, cy);
        float d0  = __fadd_rn(__fmul_rn(dx0,dx0), __fmul_rn(dy0,dy0));
        float dx1 = __fsub_rn(p.z, cx), dy1 = __fsub_rn(p.w, cy);
        float d1  = __fadd_rn(__fmul_rn(dx1,dx1), __fmul_rn(dy1,dy1));
        float2 mp;
        if (k == 0){ mp.x = d0; mp.y = d1; }
        else {
            mp = ((const float2*)min_d)[q];
            mp.x = fminf(mp.x, d0); mp.y = fminf(mp.y, d1);
        }
        ((float2*)min_d)[q] = mp;
        int g = 2*q;
        // max over min_d, tie -> lowest index (np argmax picks first); min_d >= 0
        unsigned long long k0 =
            ((unsigned long long)__float_as_uint(mp.x) << 32)
            | (unsigned long long)(0xFFFFFFFFu - (unsigned)g);
        unsigned long long k1 =
            ((unsigned long long)__float_as_uint(mp.y) << 32)
            | (unsigned long long)(0xFFFFFFFFu - (unsigned)(g+1));
        if (k0 > bk) bk = k0;
        if (k1 > bk) bk = k1;
    }
    if ((N & 1) && blockIdx.x == 0 && threadIdx.x == 0){
        int g = N-1;
        float dx = __fsub_rn(P[2*g], cx), dy = __fsub_rn(P[2*g+1], cy);
        float d  = __fadd_rn(__fmul_rn(dx,dx), __fmul_rn(dy,dy));
        float nm = (k == 0) ? d : fminf(min_d[g], d);
        min_d[g] = nm;
        unsigned long long kk =
            ((unsigned long long)__float_as_uint(nm) << 32)
            | (unsigned long long)(0xFFFFFFFFu - (unsigned)g);
        if (kk > bk) bk = kk;
    }
#pragma unroll
    for (int off = 32; off > 0; off >>= 1){
        unsigned long long o = __shfl_xor(bk, off, 64);
        if (o > bk) bk = o;
    }
    if (lane == 0) wred[wid] = bk;
    __syncthreads();
    if (threadIdx.x == 0){
        unsigned long long b = wred[0];
#pragma unroll
        for (int w = 1; w < FPST/64; ++w) if (wred[w] > b) b = wred[w];
        partials[k*FPSB + blockIdx.x] = b;
    }
}

// ---------------- kNN pass 1: sampled exponent histogram; folds FPS step 15 ----------------
__global__ __launch_bounds__(256) void hist_kernel(
    const float* __restrict__ P, int N,
    const unsigned long long* __restrict__ partials,
    float* __restrict__ cxy,
    float* __restrict__ outC,
    unsigned int* __restrict__ ghist,
    unsigned int* __restrict__ rhist)
{
    __shared__ unsigned int h[MCENT*NBINS];
    __shared__ float scx[MCENT], scy[MCENT], scs2[MCENT];
    __shared__ unsigned long long wred[4];
    __shared__ int s_cur;

    // fold FPS step 15: reduce partials[14] -> center 15 (identical key logic)
    {
        unsigned long long pb = 0ULL;
        for (int i = threadIdx.x; i < FPSB; i += 256){
            unsigned long long v = partials[14*FPSB + i];
            if (v > pb) pb = v;
        }
#pragma unroll
        for (int off = 32; off > 0; off >>= 1){
            unsigned long long o = __shfl_xor(pb, off, 64);
            if (o > pb) pb = o;
        }
        if ((threadIdx.x & 63) == 0) wred[threadIdx.x >> 6] = pb;
        __syncthreads();
        if (threadIdx.x == 0){
            unsigned long long b = wred[0];
#pragma unroll
            for (int w = 1; w < 4; ++w) if (wred[w] > b) b = wred[w];
            s_cur = (int)(0xFFFFFFFFu - (unsigned)(b & 0xFFFFFFFFu));
        }
        __syncthreads();
    }
    const int cur15 = s_cur;
    const float c15x = P[2*cur15], c15y = P[2*cur15+1];
    if (blockIdx.x == 0 && threadIdx.x == 0){
        cxy[30] = c15x; cxy[31] = c15y;
        outC[30] = c15x; outC[31] = c15y;
    }

    {
        int gi = blockIdx.x*blockDim.x + threadIdx.x;
        if (gi < MCENT*RBINS) rhist[gi] = 0u;
    }
    for (int i = threadIdx.x; i < MCENT*NBINS; i += blockDim.x) h[i] = 0u;
    if (threadIdx.x < MCENT){
        float a, b;
        if (threadIdx.x == 15){ a = c15x; b = c15y; }
        else { a = cxy[2*threadIdx.x]; b = cxy[2*threadIdx.x+1]; }
        scx[threadIdx.x] = a; scy[threadIdx.x] = b;
        scs2[threadIdx.x] = __fadd_rn(__fmul_rn(a,a), __fmul_rn(b,b));
    }
    __syncthreads();
    const int T    = gridDim.x * blockDim.x;
    const int NP16 = (N >> 1) >> 4;     // every 16th float4-pair
    for (int q = blockIdx.x*blockDim.x + threadIdx.x; q < NP16; q += T){
        float4 p = ((const float4*)P)[(size_t)q << 4];
        float ps20 = __fadd_rn(__fmul_rn(p.x,p.x), __fmul_rn(p.y,p.y));
        float ps21 = __fadd_rn(__fmul_rn(p.z,p.z), __fmul_rn(p.w,p.w));
#pragma unroll
        for (int m = 0; m < MCENT; ++m){
            // match reference expanded form: ps2 - 2*dot + cs2
            float dot0 = __fadd_rn(__fmul_rn(scx[m],p.x), __fmul_rn(scy[m],p.y));
            float d20  = __fadd_rn(__fsub_rn(ps20, __fmul_rn(2.0f,dot0)), scs2[m]);
            atomicAdd(&h[m*NBINS + (__float_as_uint(fmaxf(d20,0.0f)) >> 22)], 1u);
            float dot1 = __fadd_rn(__fmul_rn(scx[m],p.z), __fmul_rn(scy[m],p.w));
            float d21  = __fadd_rn(__fsub_rn(ps21, __fmul_rn(2.0f,dot1)), scs2[m]);
            atomicAdd(&h[m*NBINS + (__float_as_uint(fmaxf(d21,0.0f)) >> 22)], 1u);
        }
    }
    __syncthreads();
    for (int i = threadIdx.x; i < MCENT*NBINS; i += blockDim.x){
        unsigned v = h[i];
        if (v) atomicAdd(&ghist[i], v);
    }
}

// Coarse threshold from sampled hist; >=64 full points lie strictly below thrc
// (the 64 sampled ones are full points; identical __f*_rn rounding).
__global__ void thr_kernel(const unsigned int* __restrict__ ghist,
                           float* __restrict__ thr,
                           float* __restrict__ sc2){
    int m = threadIdx.x;
    if (m < MCENT){
        unsigned cum = 0; int B = NBINS-1;
        for (int b = 0; b < NBINS; ++b){
            cum += ghist[m*NBINS + b];
            if (cum >= KNN){ B = b; break; }
        }
        float t = __uint_as_float((unsigned)(B+1) << 22);
        thr[m] = t;
        sc2[m] = 255.0f / t;   // single source: refine & collect use identical bits
    }
}

// ---------------- refine: full-N linear histogram within [0, thrc), XCD-sliced ----------------
__global__ __launch_bounds__(256) void refine_kernel(
    const float* __restrict__ P, int N,
    const float* __restrict__ cxy,
    const float* __restrict__ sc2,
    unsigned int* __restrict__ rhist)
{
    __shared__ unsigned int h[MCENT*RBINS];
    __shared__ float scx[MCENT], scy[MCENT], scs2[MCENT], ssc[MCENT];
    for (int i = threadIdx.x; i < MCENT*RBINS; i += blockDim.x) h[i] = 0u;
    if (threadIdx.x < MCENT){
        float a = cxy[2*threadIdx.x], b = cxy[2*threadIdx.x+1];
        scx[threadIdx.x]=a; scy[threadIdx.x]=b;
        scs2[threadIdx.x]=__fadd_rn(__fmul_rn(a,a),__fmul_rn(b,b));
        ssc[threadIdx.x]=sc2[threadIdx.x];
    }
    __syncthreads();
    const int NP = N >> 1;
    int q0, s1, st;
    xcd_slice(NP, gridDim.x, blockIdx.x, 256, threadIdx.x, &q0, &s1, &st);
    for (int q = q0; q < s1; q += st){
        float4 p = ((const float4*)P)[q];
        float ps20 = __fadd_rn(__fmul_rn(p.x,p.x), __fmul_rn(p.y,p.y));
        float ps21 = __fadd_rn(__fmul_rn(p.z,p.z), __fmul_rn(p.w,p.w));
#pragma unroll
        for (int m = 0; m < MCENT; ++m){
            float dot0 = __fadd_rn(__fmul_rn(scx[m],p.x), __fmul_rn(scy[m],p.y));
            float d20  = __fadd_rn(__fsub_rn(ps20, __fmul_rn(2.0f,dot0)), scs2[m]);
            int b0 = (int)(fmaxf(d20, 0.0f) * ssc[m]);
            if (b0 < RBINS) atomicAdd(&h[m*RBINS + b0], 1u);
            float dot1 = __fadd_rn(__fmul_rn(scx[m],p.z), __fmul_rn(scy[m],p.w));
            float d21  = __fadd_rn(__fsub_rn(ps21, __fmul_rn(2.0f,dot1)), scs2[m]);
            int b1 = (int)(fmaxf(d21, 0.0f) * ssc[m]);
            if (b1 < RBINS) atomicAdd(&h[m*RBINS + b1], 1u);
        }
    }
    if ((N & 1) && blockIdx.x == 0 && threadIdx.x == 0){
        int g = N-1;
        float x = P[2*g], y = P[2*g+1];
        float ps2 = __fadd_rn(__fmul_rn(x,x), __fmul_rn(y,y));
        for (int m = 0; m < MCENT; ++m){
            float dot = __fadd_rn(__fmul_rn(scx[m],x), __fmul_rn(scy[m],y));
            float d2  = __fadd_rn(__fsub_rn(ps2, __fmul_rn(2.0f,dot)), scs2[m]);
            int b = (int)(fmaxf(d2, 0.0f) * ssc[m]);
            if (b < RBINS) atomicAdd(&h[m*RBINS + b], 1u);
        }
    }
    __syncthreads();
    for (int i = threadIdx.x; i < MCENT*RBINS; i += blockDim.x){
        unsigned v = h[i];
        if (v) atomicAdd(&rhist[i], v);
    }
}

// Tight bin bound: B2 = min b with cum >= 64. {d2c < thrc} maps to bins <= 255
// (255/256 slack >> float eps), so cum(0..255) >= 64 always -> B2 in [0,255].
__global__ void thr2_kernel(const unsigned int* __restrict__ rhist,
                            int* __restrict__ B2){
    int m = threadIdx.x;
    if (m < MCENT){
        unsigned cum = 0; int B = RBINS-1;
        for (int b = 0; b < RBINS; ++b){
            cum += rhist[m*RBINS + b];
            if (cum >= KNN){ B = b; break; }
        }
        B2[m] = B;
    }
}

// ---------------- kNN collect: bin(d2) <= B2 (~70 candidates/center), XCD-sliced ----------------
__global__ __launch_bounds__(256) void collect_kernel(
    const float* __restrict__ P, int N,
    const float* __restrict__ cxy,
    const float* __restrict__ sc2,
    const int* __restrict__ B2,
    unsigned int* __restrict__ cnt,
    float* __restrict__ cd2,
    int* __restrict__ cidx)
{
    __shared__ float scx[MCENT], scy[MCENT], scs2[MCENT], ssc[MCENT];
    __shared__ int sB2[MCENT];
    if (threadIdx.x < MCENT){
        float a = cxy[2*threadIdx.x], b = cxy[2*threadIdx.x+1];
        scx[threadIdx.x]=a; scy[threadIdx.x]=b;
        scs2[threadIdx.x]=__fadd_rn(__fmul_rn(a,a),__fmul_rn(b,b));
        ssc[threadIdx.x]=sc2[threadIdx.x];
        sB2[threadIdx.x]=B2[threadIdx.x];
    }
    __syncthreads();
    const int NP = N >> 1;
    int q0, s1, st;
    xcd_slice(NP, gridDim.x, blockIdx.x, 256, threadIdx.x, &q0, &s1, &st);
    for (int q = q0; q < s1; q += st){
        float4 p = ((const float4*)P)[q];
        float ps20 = __fadd_rn(__fmul_rn(p.x,p.x), __fmul_rn(p.y,p.y));
        float ps21 = __fadd_rn(__fmul_rn(p.z,p.z), __fmul_rn(p.w,p.w));
        int g = 2*q;
#pragma unroll
        for (int m = 0; m < MCENT; ++m){
            float dot0 = __fadd_rn(__fmul_rn(scx[m],p.x), __fmul_rn(scy[m],p.y));
            float d20  = __fadd_rn(__fsub_rn(ps20, __fmul_rn(2.0f,dot0)), scs2[m]);
            if ((int)(fmaxf(d20,0.0f) * ssc[m]) <= sB2[m]){
                unsigned pos = atomicAdd(&cnt[m], 1u);
                if (pos < CAP){ cd2[m*CAP+pos]=d20; cidx[m*CAP+pos]=g; }
            }
            float dot1 = __fadd_rn(__fmul_rn(scx[m],p.z), __fmul_rn(scy[m],p.w));
            float d21  = __fadd_rn(__fsub_rn(ps21, __fmul_rn(2.0f,dot1)), scs2[m]);
            if ((int)(fmaxf(d21,0.0f) * ssc[m]) <= sB2[m]){
                unsigned pos = atomicAdd(&cnt[m], 1u);
                if (pos < CAP){ cd2[m*CAP+pos]=d21; cidx[m*CAP+pos]=g+1; }
            }
        }
    }
    if ((N & 1) && blockIdx.x == 0 && threadIdx.x == 0){
        int g = N-1;
        float x = P[2*g], y = P[2*g+1];
        float ps2 = __fadd_rn(__fmul_rn(x,x), __fmul_rn(y,y));
        for (int m = 0; m < MCENT; ++m){
            float dot = __fadd_rn(__fmul_rn(scx[m],x), __fmul_rn(scy[m],y));
            float d2  = __fadd_rn(__fsub_rn(ps2, __fmul_rn(2.0f,dot)), scs2[m]);
            if ((int)(fmaxf(d2,0.0f) * ssc[m]) <= sB2[m]){
                unsigned pos = atomicAdd(&cnt[m], 1u);
                if (pos < CAP){ cd2[m*CAP+pos]=d2; cidx[m*CAP+pos]=g; }
            }
        }
    }
}

// ---------------- exact top-64 per center: rank by pairwise comparison ----------------
__global__ __launch_bounds__(256) void select_kernel(
    const unsigned int* __restrict__ cnt,
    const float* __restrict__ cd2,
    const int* __restrict__ cidx,
    int* __restrict__ nbr)
{
    const int m = blockIdx.x;
    __shared__ unsigned long long keys[CAP];
    unsigned c = cnt[m]; if (c > CAP) c = CAP;
    for (int i = threadIdx.x; i < (int)c; i += 256){
        unsigned u = __float_as_uint(cd2[m*CAP+i]);
        u = (u & 0x80000000u) ? ~u : (u | 0x80000000u);  // float -> sortable uint
        keys[i] = ((unsigned long long)u << 32)
                | (unsigned long long)(unsigned)cidx[m*CAP+i]; // tie -> lower idx
    }
    __syncthreads();
    // each candidate's exact rank = #keys smaller; keys unique (idx in low bits)
    for (int i = threadIdx.x; i < (int)c; i += 256){
        unsigned long long ki = keys[i];
        int rank = 0;
        for (int j = 0; j < (int)c; ++j) rank += (keys[j] < ki);
        if (rank < KNN) nbr[m*KNN + rank] = (int)(unsigned)(ki & 0xFFFFFFFFu);
    }
}

// ---------------- features + MLP + pooling + head: 1024 threads/center ----------------
__global__ __launch_bounds__(MLPT) void mlp_kernel(
    const float* __restrict__ P,
    const float* __restrict__ cxy,
    const int* __restrict__ nbr,
    const float* __restrict__ W1, const float* __restrict__ b1,
    const float* __restrict__ W2, const float* __restrict__ b2,
    const float* __restrict__ W3, const float* __restrict__ b3,
    const float* __restrict__ W4, const float* __restrict__ b4,
    float* __restrict__ outF)
{
    const int m = blockIdx.x;
    const int tid = threadIdx.x;
    __shared__ float feat[KNN][32];          // 8 KB (29 padded to 32)
    __shared__ float h1s[KNN][64];           // 16 KB
    __shared__ float sW1[29*64];             // 7.4 KB
    __shared__ float sW2[64*128];            // 32 KB
    __shared__ float pmax[8][128], psum[8][128]; // 8 KB
    __shared__ float z[260];
    __shared__ float part[8][128];           // 4 KB
    __shared__ float zz[128];

    // stage W2 (8192 f) and W1 (1856 f) with float4, all issued up front
    {
        const float4* s2 = (const float4*)W2;
        float4* d2 = (float4*)sW2;
        d2[tid]        = s2[tid];
        d2[tid + 1024] = s2[tid + 1024];
        if (tid < 464) ((float4*)sW1)[tid] = ((const float4*)W1)[tid];
    }

    const float cx = cxy[2*m], cy = cxy[2*m+1];
    if (tid < KNN){
        int g = nbr[m*KNN + tid];
        float dx = P[2*g]   - cx;
        float dy = P[2*g+1] - cy;
        float r  = sqrtf(dx*dx + dy*dy);
        float th = atan2f(dy, dx);
        feat[tid][0]=dx; feat[tid][1]=dy; feat[tid][2]=r;
        feat[tid][3]=sinf(th); feat[tid][4]=cosf(th);
        float fx = dx, fy = dy;      // freqs 1,2,4,8,16,32
#pragma unroll
        for (int l = 0; l < 6; ++l){
            feat[tid][5+4*l+0]=sinf(fx);
            feat[tid][5+4*l+1]=sinf(fy);
            feat[tid][5+4*l+2]=cosf(fx);
            feat[tid][5+4*l+3]=cosf(fy);
            fx += fx; fy += fy;
        }
    }
    __syncthreads();

    // h1 = gelu(per_pt @ W1 + b1): 64x64 outputs, 4 per thread
#pragma unroll
    for (int rep = 0; rep < 4; ++rep){
        int o = rep*MLPT + tid;
        int k = o >> 6, j = o & 63;
        float acc = b1[j];
#pragma unroll
        for (int c = 0; c < 29; ++c) acc += feat[k][c] * sW1[c*64 + j];
        h1s[k][j] = gelu_f(acc);
    }
    __syncthreads();

    // h2 = gelu(h1 @ W2 + b2) with fused max/mean pooling: 8 k's per thread
    {
        int j = tid & 127, kh = tid >> 7;
        float lmax = -3.402823466e+38f, lsum = 0.f;
        for (int kk = 0; kk < 8; ++kk){
            int k = kh*8 + kk;
            float acc = b2[j];
#pragma unroll 8
            for (int i = 0; i < 64; ++i) acc += h1s[k][i] * sW2[i*128 + j];
            float v = gelu_f(acc);
            lmax = fmaxf(lmax, v);
            lsum += v;
        }
        pmax[kh][j] = lmax; psum[kh][j] = lsum;
    }
    __syncthreads();
    if (tid < 128){
        float mx = pmax[0][tid], sm = psum[0][tid];
#pragma unroll
        for (int w = 1; w < 8; ++w){ mx = fmaxf(mx, pmax[w][tid]); sm += psum[w][tid]; }
        z[tid]       = mx;
        z[128 + tid] = sm * (1.0f/64.0f);
    }
    if (tid >= 128 && tid < 192){   // r stats on wave 2
        int l = tid - 128;
        float r = feat[l][2];
        float s = r, mx = r, mn = r;
        for (int off = 1; off < 64; off <<= 1){
            s  += __shfl_xor(s, off, 64);
            mx  = fmaxf(mx, __shfl_xor(mx, off, 64));
            mn  = fminf(mn, __shfl_xor(mn, off, 64));
        }
        float mean = s * (1.0f/64.0f);
        float dv = (r-mean)*(r-mean);
        for (int off = 1; off < 64; off <<= 1) dv += __shfl_xor(dv, off, 64);
        if (l == 0){
            z[256]=mean; z[257]=mx; z[258]=mn; z[259]=sqrtf(dv*(1.0f/63.0f));
        }
    }
    __syncthreads();

    // head: gelu(z @ W3 + b3) @ W4 + b4, reduction split 8 ways
    {
        int j = tid & 127, seg = tid >> 7;
        int i0  = (seg < 4) ? seg*33 : 132 + (seg-4)*32;
        int cntn = (seg < 4) ? 33 : 32;
        float acc = 0.f;
        for (int i = i0; i < i0 + cntn; ++i) acc += z[i]*W3[i*128+j];
        part[seg][j] = acc;
    }
    __syncthreads();
    if (tid < 128){
        float a = part[0][tid];
#pragma unroll
        for (int w = 1; w < 8; ++w) a += part[w][tid];
        zz[tid] = gelu_f(a + b3[tid]);
    }
    __syncthreads();
    {
        int j = tid & 127, seg = tid >> 7;
        float acc = 0.f;
#pragma unroll
        for (int i = seg*16; i < seg*16+16; ++i) acc += zz[i]*W4[i*128+j];
        part[seg][j] = acc;
    }
    __syncthreads();
    if (tid < 128){
        float a = part[0][tid];
#pragma unroll
        for (int w = 1; w < 8; ++w) a += part[w][tid];
        outF[m*128 + tid] = a + b4[tid];
    }
}

extern "C" void kernel_launch(void* const* d_in, const int* in_sizes, int n_in,
                              void* d_out, int out_size, void* d_ws, size_t ws_size,
                              hipStream_t stream)
{
    const float* P  = (const float*)d_in[0];
    const float* W1 = (const float*)d_in[1];
    const float* b1 = (const float*)d_in[2];
    const float* W2 = (const float*)d_in[3];
    const float* b2 = (const float*)d_in[4];
    const float* W3 = (const float*)d_in[5];
    const float* b3 = (const float*)d_in[6];
    const float* W4 = (const float*)d_in[7];
    const float* b4 = (const float*)d_in[8];
    int N = in_sizes[0] / 2;
    float* outF = (float*)d_out;               // [16][128]
    float* outC = outF + MCENT*128;            // [16][2]
    (void)n_in; (void)out_size; (void)ws_size;

    char* base = (char*)d_ws;
    size_t off = 0;
    auto take = [&](size_t bytes)->char*{
        char* p = base + off;
        off = (off + bytes + 255) & ~(size_t)255;
        return p;
    };
    unsigned long long* partials = (unsigned long long*)take((size_t)MCENT*FPSB*8);
    float* cxy         = (float*)take(MCENT*2*4);
    unsigned int* ghist= (unsigned int*)take(MCENT*NBINS*4);
    unsigned int* rhist= (unsigned int*)take(MCENT*RBINS*4);
    unsigned int* cnt  = (unsigned int*)take(MCENT*4);
    float* thr         = (float*)take(MCENT*4);
    float* sc2         = (float*)take(MCENT*4);
    int*   B2          = (int*)  take(MCENT*4);
    int*   nbr         = (int*)  take(MCENT*KNN*4);
    float* cd2         = (float*)take((size_t)MCENT*CAP*4);
    int*   cidx        = (int*)  take((size_t)MCENT*CAP*4);
    float* min_d       = (float*)take((size_t)N*4);

    // FPS: 15 plain launches (centers 0..14 + partials for 15);
    // hist folds the final reduction. k=0 also zero-inits ghist/cnt.
    for (int k = 0; k < MCENT-1; ++k)
        fps_step<<<FPSB, FPST, 0, stream>>>(P, N, min_d, partials, k, cxy, outC,
                                            ghist, cnt);

    hist_kernel<<<128, 256, 0, stream>>>(P, N, partials, cxy, outC, ghist, rhist);
    thr_kernel<<<1, 64, 0, stream>>>(ghist, thr, sc2);
    refine_kernel<<<256, 256, 0, stream>>>(P, N, cxy, sc2, rhist);
    thr2_kernel<<<1, 64, 0, stream>>>(rhist, B2);
    collect_kernel<<<512, 256, 0, stream>>>(P, N, cxy, sc2, B2, cnt, cd2, cidx);
    select_kernel<<<MCENT, 256, 0, stream>>>(cnt, cd2, cidx, nbr);
    mlp_kernel<<<MCENT, MLPT, 0, stream>>>(P, cxy, nbr, W1,b1,W2,b2,W3,b3,W4,b4, outF);
}

// Round 12
// 308.212 us; speedup vs baseline: 1.8431x; 1.0072x over previous
//
#include <hip/hip_runtime.h>
#include <math.h>

#define MCENT 16
#define KNN   64
#define NBINS 512
#define RBINS 256
#define CAP   7936
#define SKEYS 1024
#define FPSB  1024
#define FPST  256
#define MLPT  1024

__device__ __forceinline__ float gelu_f(float x){
    return 0.5f * x * (1.0f + erff(x * 0.70710678118654752440f));
}

// Contiguous 1/8 slice of [0,NP) per XCD (blockIdx%8 heuristic; wrong mapping
// costs only locality, never correctness).
__device__ __forceinline__ void xcd_slice(int NP, int B, int bid, int tpb, int tid,
                                          int* q0, int* s1, int* step){
    int xcd = bid & 7, j = bid >> 3, Bx = B >> 3;
    long long np = NP;
    *q0   = (int)((np * xcd) >> 3) + j*tpb + tid;
    *s1   = (int)((np * (xcd+1)) >> 3);
    *step = Bx * tpb;
}

// ---------------- FPS step k (k=0..14): kernel boundary = grid sync ----------------
// min_d stores are skipped when unchanged (identical values, less write traffic).
__global__ __launch_bounds__(FPST) void fps_step(
    const float* __restrict__ P, int N,
    float* __restrict__ min_d,
    unsigned long long* __restrict__ partials,  // [MCENT][FPSB]
    int k,
    float* __restrict__ cxy,
    float* __restrict__ outC,
    unsigned int* __restrict__ ghist,
    unsigned int* __restrict__ cnt)
{
    const int lane = threadIdx.x & 63;
    const int wid  = threadIdx.x >> 6;
    __shared__ unsigned long long wred[FPST/64];
    __shared__ int s_cur;

    if (k == 0){
        int gi = blockIdx.x*FPST + threadIdx.x;
        if (gi < MCENT*NBINS) ghist[gi] = 0u;
        if (gi < MCENT) cnt[gi] = 0u;
    }

    int cur = 0;
    if (k > 0){
        unsigned long long pb = 0ULL;
        for (int i = threadIdx.x; i < FPSB; i += FPST){
            unsigned long long v = partials[(k-1)*FPSB + i];
            if (v > pb) pb = v;
        }
#pragma unroll
        for (int off = 32; off > 0; off >>= 1){
            unsigned long long o = __shfl_xor(pb, off, 64);
            if (o > pb) pb = o;
        }
        if (lane == 0) wred[wid] = pb;
        __syncthreads();
        if (threadIdx.x == 0){
            unsigned long long b = wred[0];
#pragma unroll
            for (int w = 1; w < FPST/64; ++w) if (wred[w] > b) b = wred[w];
            s_cur = (int)(0xFFFFFFFFu - (unsigned)(b & 0xFFFFFFFFu));
        }
        __syncthreads();
        cur = s_cur;
    }

    if (blockIdx.x == 0 && threadIdx.x == 0){
        float cx = P[2*cur], cy = P[2*cur+1];
        cxy[2*k] = cx; cxy[2*k+1] = cy;
        outC[2*k] = cx; outC[2*k+1] = cy;
    }

    const float cx = P[2*cur], cy = P[2*cur+1];
    unsigned long long bk = 0ULL;
    const int NP = N >> 1;
    int q0, s1, st;
    xcd_slice(NP, gridDim.x, blockIdx.x, FPST, threadIdx.x, &q0, &s1, &st);
    for (int q = q0; q < s1; q += st){
        float4 p = ((const float4*)P)[q];           // (x0,y0,x1,y1)
        // match np: (dx*dx) + (dy*dy), no fma contraction; min is exact
        float dx0 = __fsub_rn(p.x, cx), dy0 = __fsub_rn(p.y, cy);
        float d0  = __fadd_rn(__fmul_rn(dx0,dx0), __fmul_rn(dy0,dy0));
        float dx1 = __fsub_rn(p.z, cx), dy1 = __fsub_rn(p.w, cy);
        float d1  = __fadd_rn(__fmul_rn(dx1,dx1), __fmul_rn(dy1,dy1));
        float mx, my;
        if (k == 0){
            mx = d0; my = d1;
            ((float2*)min_d)[q] = make_float2(mx, my);
        } else {
            float2 mo = ((const float2*)min_d)[q];
            mx = fminf(mo.x, d0); my = fminf(mo.y, d1);
            if (mx != mo.x || my != mo.y)          // store only if changed
                ((float2*)min_d)[q] = make_float2(mx, my);
        }
        int g = 2*q;
        // max over min_d, tie -> lowest index (np argmax picks first); min_d >= 0
        unsigned long long k0 =
            ((unsigned long long)__float_as_uint(mx) << 32)
            | (unsigned long long)(0xFFFFFFFFu - (unsigned)g);
        unsigned long long k1 =
            ((unsigned long long)__float_as_uint(my) << 32)
            | (unsigned long long)(0xFFFFFFFFu - (unsigned)(g+1));
        if (k0 > bk) bk = k0;
        if (k1 > bk) bk = k1;
    }
    if ((N & 1) && blockIdx.x == 0 && threadIdx.x == 0){
        int g = N-1;
        float dx = __fsub_rn(P[2*g], cx), dy = __fsub_rn(P[2*g+1], cy);
        float d  = __fadd_rn(__fmul_rn(dx,dx), __fmul_rn(dy,dy));
        float nm = (k == 0) ? d : fminf(min_d[g], d);
        min_d[g] = nm;
        unsigned long long kk =
            ((unsigned long long)__float_as_uint(nm) << 32)
            | (unsigned long long)(0xFFFFFFFFu - (unsigned)g);
        if (kk > bk) bk = kk;
    }
#pragma unroll
    for (int off = 32; off > 0; off >>= 1){
        unsigned long long o = __shfl_xor(bk, off, 64);
        if (o > bk) bk = o;
    }
    if (lane == 0) wred[wid] = bk;
    __syncthreads();
    if (threadIdx.x == 0){
        unsigned long long b = wred[0];
#pragma unroll
        for (int w = 1; w < FPST/64; ++w) if (wred[w] > b) b = wred[w];
        partials[k*FPSB + blockIdx.x] = b;
    }
}

// ---------------- kNN pass 1: sampled exponent histogram; folds FPS step 15 ----------------
__global__ __launch_bounds__(256) void hist_kernel(
    const float* __restrict__ P, int N,
    const unsigned long long* __restrict__ partials,
    float* __restrict__ cxy,
    float* __restrict__ outC,
    unsigned int* __restrict__ ghist,
    unsigned int* __restrict__ rhist)
{
    __shared__ unsigned int h[MCENT*NBINS];
    __shared__ float scx[MCENT], scy[MCENT], scs2[MCENT];
    __shared__ unsigned long long wred[4];
    __shared__ int s_cur;

    // fold FPS step 15: reduce partials[14] -> center 15 (identical key logic)
    {
        unsigned long long pb = 0ULL;
        for (int i = threadIdx.x; i < FPSB; i += 256){
            unsigned long long v = partials[14*FPSB + i];
            if (v > pb) pb = v;
        }
#pragma unroll
        for (int off = 32; off > 0; off >>= 1){
            unsigned long long o = __shfl_xor(pb, off, 64);
            if (o > pb) pb = o;
        }
        if ((threadIdx.x & 63) == 0) wred[threadIdx.x >> 6] = pb;
        __syncthreads();
        if (threadIdx.x == 0){
            unsigned long long b = wred[0];
#pragma unroll
            for (int w = 1; w < 4; ++w) if (wred[w] > b) b = wred[w];
            s_cur = (int)(0xFFFFFFFFu - (unsigned)(b & 0xFFFFFFFFu));
        }
        __syncthreads();
    }
    const int cur15 = s_cur;
    const float c15x = P[2*cur15], c15y = P[2*cur15+1];
    if (blockIdx.x == 0 && threadIdx.x == 0){
        cxy[30] = c15x; cxy[31] = c15y;
        outC[30] = c15x; outC[31] = c15y;
    }

    {
        int gi = blockIdx.x*blockDim.x + threadIdx.x;
        if (gi < MCENT*RBINS) rhist[gi] = 0u;
    }
    for (int i = threadIdx.x; i < MCENT*NBINS; i += blockDim.x) h[i] = 0u;
    if (threadIdx.x < MCENT){
        float a, b;
        if (threadIdx.x == 15){ a = c15x; b = c15y; }
        else { a = cxy[2*threadIdx.x]; b = cxy[2*threadIdx.x+1]; }
        scx[threadIdx.x] = a; scy[threadIdx.x] = b;
        scs2[threadIdx.x] = __fadd_rn(__fmul_rn(a,a), __fmul_rn(b,b));
    }
    __syncthreads();
    const int T    = gridDim.x * blockDim.x;
    const int NP16 = (N >> 1) >> 4;     // every 16th float4-pair
    for (int q = blockIdx.x*blockDim.x + threadIdx.x; q < NP16; q += T){
        float4 p = ((const float4*)P)[(size_t)q << 4];
        float ps20 = __fadd_rn(__fmul_rn(p.x,p.x), __fmul_rn(p.y,p.y));
        float ps21 = __fadd_rn(__fmul_rn(p.z,p.z), __fmul_rn(p.w,p.w));
#pragma unroll
        for (int m = 0; m < MCENT; ++m){
            // match reference expanded form: ps2 - 2*dot + cs2
            float dot0 = __fadd_rn(__fmul_rn(scx[m],p.x), __fmul_rn(scy[m],p.y));
            float d20  = __fadd_rn(__fsub_rn(ps20, __fmul_rn(2.0f,dot0)), scs2[m]);
            atomicAdd(&h[m*NBINS + (__float_as_uint(fmaxf(d20,0.0f)) >> 22)], 1u);
            float dot1 = __fadd_rn(__fmul_rn(scx[m],p.z), __fmul_rn(scy[m],p.w));
            float d21  = __fadd_rn(__fsub_rn(ps21, __fmul_rn(2.0f,dot1)), scs2[m]);
            atomicAdd(&h[m*NBINS + (__float_as_uint(fmaxf(d21,0.0f)) >> 22)], 1u);
        }
    }
    __syncthreads();
    for (int i = threadIdx.x; i < MCENT*NBINS; i += blockDim.x){
        unsigned v = h[i];
        if (v) atomicAdd(&ghist[i], v);
    }
}

// sc2 from ghist: identical expression everywhere -> identical bits.
__device__ __forceinline__ void compute_ssc(const unsigned* gh, int tid, float* ssc){
    if (tid < MCENT){
        unsigned cum = 0; int B = NBINS-1;
        for (int b = 0; b < NBINS; ++b){
            cum += gh[tid*NBINS + b];
            if (cum >= KNN){ B = b; break; }
        }
        ssc[tid] = 255.0f / __uint_as_float((unsigned)(B+1) << 22);
    }
}

// ---------------- refine: full-N linear histogram within [0, thrc); folds thr ----------------
__global__ __launch_bounds__(256) void refine_kernel(
    const float* __restrict__ P, int N,
    const float* __restrict__ cxy,
    const unsigned int* __restrict__ ghist,
    unsigned int* __restrict__ rhist)
{
    __shared__ unsigned int gh[MCENT*NBINS];   // 32 KB staged ghist
    __shared__ unsigned int h[MCENT*RBINS];    // 16 KB
    __shared__ float scx[MCENT], scy[MCENT], scs2[MCENT], ssc[MCENT];
    for (int i = threadIdx.x; i < MCENT*NBINS; i += 256) gh[i] = ghist[i];
    for (int i = threadIdx.x; i < MCENT*RBINS; i += 256) h[i] = 0u;
    if (threadIdx.x < MCENT){
        float a = cxy[2*threadIdx.x], b = cxy[2*threadIdx.x+1];
        scx[threadIdx.x]=a; scy[threadIdx.x]=b;
        scs2[threadIdx.x]=__fadd_rn(__fmul_rn(a,a),__fmul_rn(b,b));
    }
    __syncthreads();
    compute_ssc(gh, threadIdx.x, ssc);
    __syncthreads();
    const int NP = N >> 1;
    int q0, s1, st;
    xcd_slice(NP, gridDim.x, blockIdx.x, 256, threadIdx.x, &q0, &s1, &st);
    for (int q = q0; q < s1; q += st){
        float4 p = ((const float4*)P)[q];
        float ps20 = __fadd_rn(__fmul_rn(p.x,p.x), __fmul_rn(p.y,p.y));
        float ps21 = __fadd_rn(__fmul_rn(p.z,p.z), __fmul_rn(p.w,p.w));
#pragma unroll
        for (int m = 0; m < MCENT; ++m){
            float dot0 = __fadd_rn(__fmul_rn(scx[m],p.x), __fmul_rn(scy[m],p.y));
            float d20  = __fadd_rn(__fsub_rn(ps20, __fmul_rn(2.0f,dot0)), scs2[m]);
            int b0 = (int)(fmaxf(d20, 0.0f) * ssc[m]);
            if (b0 < RBINS) atomicAdd(&h[m*RBINS + b0], 1u);
            float dot1 = __fadd_rn(__fmul_rn(scx[m],p.z), __fmul_rn(scy[m],p.w));
            float d21  = __fadd_rn(__fsub_rn(ps21, __fmul_rn(2.0f,dot1)), scs2[m]);
            int b1 = (int)(fmaxf(d21, 0.0f) * ssc[m]);
            if (b1 < RBINS) atomicAdd(&h[m*RBINS + b1], 1u);
        }
    }
    if ((N & 1) && blockIdx.x == 0 && threadIdx.x == 0){
        int g = N-1;
        float x = P[2*g], y = P[2*g+1];
        float ps2 = __fadd_rn(__fmul_rn(x,x), __fmul_rn(y,y));
        for (int m = 0; m < MCENT; ++m){
            float dot = __fadd_rn(__fmul_rn(scx[m],x), __fmul_rn(scy[m],y));
            float d2  = __fadd_rn(__fsub_rn(ps2, __fmul_rn(2.0f,dot)), scs2[m]);
            int b = (int)(fmaxf(d2, 0.0f) * ssc[m]);
            if (b < RBINS) atomicAdd(&h[m*RBINS + b], 1u);
        }
    }
    __syncthreads();
    for (int i = threadIdx.x; i < MCENT*RBINS; i += blockDim.x){
        unsigned v = h[i];
        if (v) atomicAdd(&rhist[i], v);
    }
}

// ---------------- collect: bin(d2) <= B2 (~70-150/center); folds thr+thr2 ----------------
__global__ __launch_bounds__(256) void collect_kernel(
    const float* __restrict__ P, int N,
    const float* __restrict__ cxy,
    const unsigned int* __restrict__ ghist,
    const unsigned int* __restrict__ rhist,
    unsigned int* __restrict__ cnt,
    float* __restrict__ cd2,
    int* __restrict__ cidx)
{
    __shared__ unsigned int gh[MCENT*NBINS];   // 32 KB
    __shared__ unsigned int rh[MCENT*RBINS];   // 16 KB
    __shared__ float scx[MCENT], scy[MCENT], scs2[MCENT], ssc[MCENT];
    __shared__ int sB2[MCENT];
    for (int i = threadIdx.x; i < MCENT*NBINS; i += 256) gh[i] = ghist[i];
    for (int i = threadIdx.x; i < MCENT*RBINS; i += 256) rh[i] = rhist[i];
    if (threadIdx.x < MCENT){
        float a = cxy[2*threadIdx.x], b = cxy[2*threadIdx.x+1];
        scx[threadIdx.x]=a; scy[threadIdx.x]=b;
        scs2[threadIdx.x]=__fadd_rn(__fmul_rn(a,a),__fmul_rn(b,b));
    }
    __syncthreads();
    compute_ssc(gh, threadIdx.x, ssc);
    if (threadIdx.x < MCENT){
        unsigned cum = 0; int B = RBINS-1;
        for (int b = 0; b < RBINS; ++b){
            cum += rh[threadIdx.x*RBINS + b];
            if (cum >= KNN){ B = b; break; }
        }
        sB2[threadIdx.x] = B;
    }
    __syncthreads();
    const int NP = N >> 1;
    int q0, s1, st;
    xcd_slice(NP, gridDim.x, blockIdx.x, 256, threadIdx.x, &q0, &s1, &st);
    for (int q = q0; q < s1; q += st){
        float4 p = ((const float4*)P)[q];
        float ps20 = __fadd_rn(__fmul_rn(p.x,p.x), __fmul_rn(p.y,p.y));
        float ps21 = __fadd_rn(__fmul_rn(p.z,p.z), __fmul_rn(p.w,p.w));
        int g = 2*q;
#pragma unroll
        for (int m = 0; m < MCENT; ++m){
            float dot0 = __fadd_rn(__fmul_rn(scx[m],p.x), __fmul_rn(scy[m],p.y));
            float d20  = __fadd_rn(__fsub_rn(ps20, __fmul_rn(2.0f,dot0)), scs2[m]);
            if ((int)(fmaxf(d20,0.0f) * ssc[m]) <= sB2[m]){
                unsigned pos = atomicAdd(&cnt[m], 1u);
                if (pos < CAP){ cd2[m*CAP+pos]=d20; cidx[m*CAP+pos]=g; }
            }
            float dot1 = __fadd_rn(__fmul_rn(scx[m],p.z), __fmul_rn(scy[m],p.w));
            float d21  = __fadd_rn(__fsub_rn(ps21, __fmul_rn(2.0f,dot1)), scs2[m]);
            if ((int)(fmaxf(d21,0.0f) * ssc[m]) <= sB2[m]){
                unsigned pos = atomicAdd(&cnt[m], 1u);
                if (pos < CAP){ cd2[m*CAP+pos]=d21; cidx[m*CAP+pos]=g+1; }
            }
        }
    }
    if ((N & 1) && blockIdx.x == 0 && threadIdx.x == 0){
        int g = N-1;
        float x = P[2*g], y = P[2*g+1];
        float ps2 = __fadd_rn(__fmul_rn(x,x), __fmul_rn(y,y));
        for (int m = 0; m < MCENT; ++m){
            float dot = __fadd_rn(__fmul_rn(scx[m],x), __fmul_rn(scy[m],y));
            float d2  = __fadd_rn(__fsub_rn(ps2, __fmul_rn(2.0f,dot)), scs2[m]);
            if ((int)(fmaxf(d2,0.0f) * ssc[m]) <= sB2[m]){
                unsigned pos = atomicAdd(&cnt[m], 1u);
                if (pos < CAP){ cd2[m*CAP+pos]=d2; cidx[m*CAP+pos]=g; }
            }
        }
    }
}

// ---------------- fused select + features + MLP: 1024 threads/center ----------------
__global__ __launch_bounds__(MLPT) void mlp_kernel(
    const float* __restrict__ P,
    const float* __restrict__ cxy,
    const unsigned int* __restrict__ cnt,
    const float* __restrict__ cd2,
    const int* __restrict__ cidx,
    const float* __restrict__ W1, const float* __restrict__ b1,
    const float* __restrict__ W2, const float* __restrict__ b2,
    const float* __restrict__ W3, const float* __restrict__ b3,
    const float* __restrict__ W4, const float* __restrict__ b4,
    float* __restrict__ outF)
{
    const int m = blockIdx.x;
    const int tid = threadIdx.x;
    __shared__ float feat[KNN][32];          // 8 KB (29 padded to 32)
    __shared__ float h1s[KNN][64];           // 16 KB
    __shared__ float sW1[29*64];             // 7.4 KB
    __shared__ float sW2[64*128];            // 32 KB
    __shared__ float pmax[8][128], psum[8][128]; // 8 KB
    __shared__ float z[260];
    __shared__ float part[8][128];           // 4 KB
    __shared__ float zz[128];
    __shared__ unsigned long long kkeys[SKEYS]; // 8 KB
    __shared__ int snbr[KNN];

    // stage W2 (8192 f) and W1 (1856 f) with float4, all issued up front
    {
        const float4* s2 = (const float4*)W2;
        float4* d2 = (float4*)sW2;
        d2[tid]        = s2[tid];
        d2[tid + 1024] = s2[tid + 1024];
        if (tid < 464) ((float4*)sW1)[tid] = ((const float4*)W1)[tid];
    }

    // ---- selection: exact rank over candidates (keys unique: idx in low bits) ----
    unsigned c = cnt[m]; if (c > CAP) c = CAP;
    if (c <= SKEYS){
        if (tid < (int)c){
            unsigned u = __float_as_uint(cd2[m*CAP+tid]);
            u = (u & 0x80000000u) ? ~u : (u | 0x80000000u);  // float -> sortable
            kkeys[tid] = ((unsigned long long)u << 32)
                       | (unsigned long long)(unsigned)cidx[m*CAP+tid];
        }
        __syncthreads();
        if (tid < (int)c){
            unsigned long long ki = kkeys[tid];
            int rank = 0;
            for (int j = 0; j < (int)c; ++j) rank += (kkeys[j] < ki);
            if (rank < KNN) snbr[rank] = (int)(unsigned)(ki & 0xFFFFFFFFu);
        }
    } else {
        // exact global fallback (not expected to execute)
        for (int i = tid; i < (int)c; i += MLPT){
            unsigned ui = __float_as_uint(cd2[m*CAP+i]);
            ui = (ui & 0x80000000u) ? ~ui : (ui | 0x80000000u);
            unsigned long long ki = ((unsigned long long)ui << 32)
                                  | (unsigned long long)(unsigned)cidx[m*CAP+i];
            int rank = 0;
            for (int j = 0; j < (int)c; ++j){
                unsigned uj = __float_as_uint(cd2[m*CAP+j]);
                uj = (uj & 0x80000000u) ? ~uj : (uj | 0x80000000u);
                unsigned long long kj = ((unsigned long long)uj << 32)
                                      | (unsigned long long)(unsigned)cidx[m*CAP+j];
                rank += (kj < ki);
            }
            if (rank < KNN) snbr[rank] = (int)(unsigned)(ki & 0xFFFFFFFFu);
        }
    }
    __syncthreads();

    const float cx = cxy[2*m], cy = cxy[2*m+1];
    if (tid < KNN){
        int g = snbr[tid];
        float dx = P[2*g]   - cx;
        float dy = P[2*g+1] - cy;
        float r  = sqrtf(dx*dx + dy*dy);
        float th = atan2f(dy, dx);
        feat[tid][0]=dx; feat[tid][1]=dy; feat[tid][2]=r;
        feat[tid][3]=sinf(th); feat[tid][4]=cosf(th);
        float fx = dx, fy = dy;      // freqs 1,2,4,8,16,32
#pragma unroll
        for (int l = 0; l < 6; ++l){
            feat[tid][5+4*l+0]=sinf(fx);
            feat[tid][5+4*l+1]=sinf(fy);
            feat[tid][5+4*l+2]=cosf(fx);
            feat[tid][5+4*l+3]=cosf(fy);
            fx += fx; fy += fy;
        }
    }
    __syncthreads();

    // h1 = gelu(per_pt @ W1 + b1): 64x64 outputs, 4 per thread
#pragma unroll
    for (int rep = 0; rep < 4; ++rep){
        int o = rep*MLPT + tid;
        int k = o >> 6, j = o & 63;
        float acc = b1[j];
#pragma unroll
        for (int cc = 0; cc < 29; ++cc) acc += feat[k][cc] * sW1[cc*64 + j];
        h1s[k][j] = gelu_f(acc);
    }
    __syncthreads();

    // h2 = gelu(h1 @ W2 + b2) with fused max/mean pooling: 8 k's per thread
    {
        int j = tid & 127, kh = tid >> 7;
        float lmax = -3.402823466e+38f, lsum = 0.f;
        for (int kk = 0; kk < 8; ++kk){
            int k = kh*8 + kk;
            float acc = b2[j];
#pragma unroll 8
            for (int i = 0; i < 64; ++i) acc += h1s[k][i] * sW2[i*128 + j];
            float v = gelu_f(acc);
            lmax = fmaxf(lmax, v);
            lsum += v;
        }
        pmax[kh][j] = lmax; psum[kh][j] = lsum;
    }
    __syncthreads();
    if (tid < 128){
        float mx = pmax[0][tid], sm = psum[0][tid];
#pragma unroll
        for (int w = 1; w < 8; ++w){ mx = fmaxf(mx, pmax[w][tid]); sm += psum[w][tid]; }
        z[tid]       = mx;
        z[128 + tid] = sm * (1.0f/64.0f);
    }
    if (tid >= 128 && tid < 192){   // r stats on wave 2
        int l = tid - 128;
        float r = feat[l][2];
        float s = r, mx = r, mn = r;
        for (int off = 1; off < 64; off <<= 1){
            s  += __shfl_xor(s, off, 64);
            mx  = fmaxf(mx, __shfl_xor(mx, off, 64));
            mn  = fminf(mn, __shfl_xor(mn, off, 64));
        }
        float mean = s * (1.0f/64.0f);
        float dv = (r-mean)*(r-mean);
        for (int off = 1; off < 64; off <<= 1) dv += __shfl_xor(dv, off, 64);
        if (l == 0){
            z[256]=mean; z[257]=mx; z[258]=mn; z[259]=sqrtf(dv*(1.0f/63.0f));
        }
    }
    __syncthreads();

    // head: gelu(z @ W3 + b3) @ W4 + b4, reduction split 8 ways
    {
        int j = tid & 127, seg = tid >> 7;
        int i0  = (seg < 4) ? seg*33 : 132 + (seg-4)*32;
        int cntn = (seg < 4) ? 33 : 32;
        float acc = 0.f;
        for (int i = i0; i < i0 + cntn; ++i) acc += z[i]*W3[i*128+j];
        part[seg][j] = acc;
    }
    __syncthreads();
    if (tid < 128){
        float a = part[0][tid];
#pragma unroll
        for (int w = 1; w < 8; ++w) a += part[w][tid];
        zz[tid] = gelu_f(a + b3[tid]);
    }
    __syncthreads();
    {
        int j = tid & 127, seg = tid >> 7;
        float acc = 0.f;
#pragma unroll
        for (int i = seg*16; i < seg*16+16; ++i) acc += zz[i]*W4[i*128+j];
        part[seg][j] = acc;
    }
    __syncthreads();
    if (tid < 128){
        float a = part[0][tid];
#pragma unroll
        for (int w = 1; w < 8; ++w) a += part[w][tid];
        outF[m*128 + tid] = a + b4[tid];
    }
}

extern "C" void kernel_launch(void* const* d_in, const int* in_sizes, int n_in,
                              void* d_out, int out_size, void* d_ws, size_t ws_size,
                              hipStream_t stream)
{
    const float* P  = (const float*)d_in[0];
    const float* W1 = (const float*)d_in[1];
    const float* b1 = (const float*)d_in[2];
    const float* W2 = (const float*)d_in[3];
    const float* b2 = (const float*)d_in[4];
    const float* W3 = (const float*)d_in[5];
    const float* b3 = (const float*)d_in[6];
    const float* W4 = (const float*)d_in[7];
    const float* b4 = (const float*)d_in[8];
    int N = in_sizes[0] / 2;
    float* outF = (float*)d_out;               // [16][128]
    float* outC = outF + MCENT*128;            // [16][2]
    (void)n_in; (void)out_size; (void)ws_size;

    char* base = (char*)d_ws;
    size_t off = 0;
    auto take = [&](size_t bytes)->char*{
        char* p = base + off;
        off = (off + bytes + 255) & ~(size_t)255;
        return p;
    };
    unsigned long long* partials = (unsigned long long*)take((size_t)MCENT*FPSB*8);
    float* cxy         = (float*)take(MCENT*2*4);
    unsigned int* ghist= (unsigned int*)take(MCENT*NBINS*4);
    unsigned int* rhist= (unsigned int*)take(MCENT*RBINS*4);
    unsigned int* cnt  = (unsigned int*)take(MCENT*4);
    float* cd2         = (float*)take((size_t)MCENT*CAP*4);
    int*   cidx        = (int*)  take((size_t)MCENT*CAP*4);
    float* min_d       = (float*)take((size_t)N*4);

    // FPS: 15 plain launches (centers 0..14 + partials for 15);
    // hist folds the final reduction. k=0 also zero-inits ghist/cnt.
    for (int k = 0; k < MCENT-1; ++k)
        fps_step<<<FPSB, FPST, 0, stream>>>(P, N, min_d, partials, k, cxy, outC,
                                            ghist, cnt);

    hist_kernel<<<128, 256, 0, stream>>>(P, N, partials, cxy, outC, ghist, rhist);
    refine_kernel<<<256, 256, 0, stream>>>(P, N, cxy, ghist, rhist);
    collect_kernel<<<512, 256, 0, stream>>>(P, N, cxy, ghist, rhist, cnt, cd2, cidx);
    mlp_kernel<<<MCENT, MLPT, 0, stream>>>(P, cxy, cnt, cd2, cidx,
                                           W1,b1,W2,b2,W3,b3,W4,b4, outF);
}